// Round 6
// baseline (628.980 us; speedup 1.0000x reference)
//
#include <hip/hip_runtime.h>
#include <cstdint>
#include <cstddef>

// ConvVFE: voxelize -> per-voxel mean -> MLP(10->32)+BN+ReLU -> voxel max
// -> concat -> MLP(64->128)+BN+ReLU -> voxel max ; plus voxel coords.
//
// R10: R9 = 595us best; kB 170us top (VALU 55, Mfma 7.6, FETCH 44MB@260GB/s,
// occ 28 -> ~45% stall). Cause: frag loads (dependent vS->xmaxV chain) issue
// at tile top and are consumed immediately by MFMA -> latency exposed each
// tile. Change (single, T14 pattern):
//  - unconditional frag loads: k5 writes zero rows for pad slots; xmaxV has
//    a zero row at index V; load_afrags uses branch-free vC = v<0 ? V : v.
//  - kB prefetches the NEXT tile's fragments right after barrier B2, so the
//    global-load chain hides under the ~1000-cyc gather phase.
//  - kA gets the branch-free load too. Everything else identical to R9.
// (Evaluated and scrapped: merging kA into kB via monotone-BN -- k_final's
//  224MB pass ~= kA's cost; R6 vs R9 totals confirm it's a wash.)

constexpr int M_IDS  = 220000;
constexpr int CH     = 256;
constexpr int NCHUNK = (M_IDS + CH - 1) / CH;   // 860
constexpr int NBA    = 1024;                    // kA grid / stats partials
constexpr int NBB    = 2048;                    // kB grid
constexpr int ELS2   = 132;                     // els row stride (u16)

typedef __attribute__((ext_vector_type(8))) __bf16          bf16x8;
typedef __attribute__((ext_vector_type(8))) unsigned short  u16x8;
typedef __attribute__((ext_vector_type(4))) float           f32x4;

union U8 { u16x8 u; bf16x8 b; };

__device__ __forceinline__ uint16_t f2b(float f) {
    uint32_t u = __float_as_uint(f);
    u += 0x7fffu + ((u >> 16) & 1u);
    return (uint16_t)(u >> 16);
}
__device__ __forceinline__ float b2f(uint16_t h) {
    return __uint_as_float(((uint32_t)h) << 16);
}

__device__ __forceinline__ f32x4 mfma16(bf16x8 a, bf16x8 b, f32x4 c) {
    return __builtin_amdgcn_mfma_f32_16x16x32_bf16(a, b, c, 0, 0, 0);
}

// ---------------------------------------------------------------- voxel id (shared by k1/k3)
__device__ __forceinline__ int voxel_id(const float* __restrict__ p) {
    float b = p[0], x = p[1], y = p[2], z = p[3];
    float fx = floorf((x - 0.0f) / 0.32f);
    float fy = floorf((y + 40.0f) / 0.32f);
    float fz = floorf((z + 3.0f) / 4.0f);
    bool ok = (fx >= 0.0f) && (fx < 220.0f) && (fy >= 0.0f) && (fy < 250.0f) &&
              (fz >= 0.0f) && (fz < 1.0f);
    if (!ok) return -1;
    return (int)b * 55000 + (int)fx * 250 + (int)fy + (int)fz;
}

// ---------------------------------------------------------------- k1: histogram only
__global__ void k1_count(const float* __restrict__ pts, int* __restrict__ cnt, int N)
{
    int i = blockIdx.x * blockDim.x + threadIdx.x;
    if (i >= N) return;
    int m = voxel_id(pts + (size_t)i * 5);
    if (m >= 0) atomicAdd(&cnt[m], 1);
}

// ---------------------------------------------------------------- k2: two-level scans
__global__ void k2a_tot(const int* __restrict__ cnt, int* __restrict__ totO,
                        int* __restrict__ totC, int* __restrict__ np)
{
    __shared__ int so[CH], sc[CH];
    int t = threadIdx.x;
    int id = blockIdx.x * CH + t;
    int c = (id < M_IDS) ? cnt[id] : 0;
    so[t] = (c > 0) ? 1 : 0;
    sc[t] = c;
    __syncthreads();
    for (int s = CH / 2; s > 0; s >>= 1) {
        if (t < s) { so[t] += so[t + s]; sc[t] += sc[t + s]; }
        __syncthreads();
    }
    if (t == 0) { totO[blockIdx.x] = so[0]; totC[blockIdx.x] = sc[0]; atomicAdd(np, sc[0]); }
}

__global__ void k2b_scan(const int* __restrict__ totO, const int* __restrict__ totC,
                         int* __restrict__ baseO, int* __restrict__ baseC)
{
    __shared__ int a[1024], bb[1024];
    int t = threadIdx.x;
    int vo = (t < NCHUNK) ? totO[t] : 0;
    int vc = (t < NCHUNK) ? totC[t] : 0;
    a[t] = vo; bb[t] = vc;
    __syncthreads();
    for (int off = 1; off < 1024; off <<= 1) {
        int xa = (t >= off) ? a[t - off] : 0;
        int xb = (t >= off) ? bb[t - off] : 0;
        __syncthreads();
        a[t] += xa; bb[t] += xb;
        __syncthreads();
    }
    baseO[t] = a[t] - vo;   // exclusive
    baseC[t] = bb[t] - vc;
}

__global__ void k2c_index(const int* __restrict__ cnt, const int* __restrict__ baseO,
                          const int* __restrict__ baseC, int* __restrict__ idxArr,
                          int* __restrict__ bOff, int* __restrict__ vOff,
                          int* __restrict__ vCnt, float* __restrict__ outCoords)
{
    __shared__ int a[CH], bb[CH];
    int t = threadIdx.x;
    int id = blockIdx.x * CH + t;
    int c = (id < M_IDS) ? cnt[id] : 0;
    int occ = (c > 0) ? 1 : 0;
    a[t] = occ; bb[t] = c;
    __syncthreads();
    for (int off = 1; off < CH; off <<= 1) {
        int xa = (t >= off) ? a[t - off] : 0;
        int xb = (t >= off) ? bb[t - off] : 0;
        __syncthreads();
        a[t] += xa; bb[t] += xb;
        __syncthreads();
    }
    if (id >= M_IDS) return;
    int g  = baseO[blockIdx.x] + a[t] - occ;
    int bo = baseC[blockIdx.x] + bb[t] - c;
    idxArr[id] = g;
    bOff[id]   = bo;
    if (occ) {
        vOff[g] = bo;
        vCnt[g] = c;
        int b2 = id / 55000;
        int rm = id % 55000;
        int cx = rm / 250;
        int cy = rm % 250;
        outCoords[(size_t)g * 4 + 0] = (float)b2;
        outCoords[(size_t)g * 4 + 1] = 0.0f;
        outCoords[(size_t)g * 4 + 2] = (float)cy;
        outCoords[(size_t)g * 4 + 3] = (float)cx;
    }
}

// ---------------------------------------------------------------- k3: scatter point payload to sorted order
__global__ void k3_order(const float* __restrict__ pts, const int* __restrict__ bOff,
                         const int* __restrict__ idxArr, int* __restrict__ cursor,
                         float4* __restrict__ pts4, int* __restrict__ vS, int N)
{
    int i = blockIdx.x * blockDim.x + threadIdx.x;
    if (i >= N) return;
    const float* p = pts + (size_t)i * 5;
    int m = voxel_id(p);
    if (m < 0) return;
    int slot = atomicAdd(&cursor[m], 1);
    int j = bOff[m] + slot;
    pts4[j] = make_float4(p[1], p[2], p[3], p[4]);
    vS[j]   = idxArr[m];
}

// ---------------------------------------------------------------- k4: per-voxel xyz mean (contiguous)
__global__ void k4_mean(const float4* __restrict__ pts4, const int* __restrict__ vOff,
                        const int* __restrict__ vCnt, float4* __restrict__ meanArr, int V)
{
    int g = blockIdx.x * blockDim.x + threadIdx.x;
    if (g >= V) return;
    int off = vOff[g], c = vCnt[g];
    float sx = 0.0f, sy = 0.0f, sz = 0.0f;
    for (int p = 0; p < c; p++) {
        float4 q = pts4[off + p];
        sx += q.x; sy += q.y; sz += q.z;
    }
    float ic = 1.0f / (float)c;
    meanArr[g] = make_float4(sx * ic, sy * ic, sz * ic, 0.0f);
}

// ---------------------------------------------------------------- k5: y0 = feats @ w0 (raw bf16, contiguous) + BN0 stats
__global__ __launch_bounds__(256)
void k5_y0(const float4* __restrict__ pts4, const float* __restrict__ w0,
           const int* __restrict__ vS, const float4* __restrict__ meanArr,
           uint16_t* __restrict__ XpL, float* __restrict__ stats0, int Npad)
{
    __shared__ float sl[64];
    int t = threadIdx.x;
    if (t < 64) sl[t] = 0.0f;
    __syncthreads();
    float s[32], q[32];
#pragma unroll
    for (int c = 0; c < 32; c++) { s[c] = 0.0f; q[c] = 0.0f; }

    for (int j = blockIdx.x * 256 + t; j < Npad; j += gridDim.x * 256) {
        int v = vS[j];
        uint4* rp = (uint4*)(XpL + (size_t)j * 32);
        if (v < 0) {                     // pad slot: explicit zero row (enables
            uint4 z = make_uint4(0u, 0u, 0u, 0u);   // unconditional frag loads)
            rp[0] = z; rp[1] = z; rp[2] = z; rp[3] = z;
            continue;
        }
        float4 P = pts4[j];
        float4 mn = meanArr[v];
        float x = P.x, y = P.y, z = P.z, it = P.w;
        float fx = floorf(x / 0.32f);
        float fy = floorf((y + 40.0f) / 0.32f);
        float f[10];
        f[0] = x; f[1] = y; f[2] = z; f[3] = it;
        f[4] = x - mn.x; f[5] = y - mn.y; f[6] = z - mn.z;
        f[7] = x - (fx * 0.32f + 0.16f);
        f[8] = y - (fy * 0.32f - 39.84f);
        f[9] = z + 1.0f;
        float y0[32];
#pragma unroll
        for (int c = 0; c < 32; c++) y0[c] = 0.0f;
#pragma unroll
        for (int d = 0; d < 10; d++) {
            float fd = f[d];
#pragma unroll
            for (int c = 0; c < 32; c++) y0[c] += fd * w0[d * 32 + c];
        }
        uint32_t pk[16];
#pragma unroll
        for (int k = 0; k < 16; k++)
            pk[k] = (uint32_t)f2b(y0[2 * k]) | ((uint32_t)f2b(y0[2 * k + 1]) << 16);
        rp[0] = make_uint4(pk[0], pk[1], pk[2], pk[3]);
        rp[1] = make_uint4(pk[4], pk[5], pk[6], pk[7]);
        rp[2] = make_uint4(pk[8], pk[9], pk[10], pk[11]);
        rp[3] = make_uint4(pk[12], pk[13], pk[14], pk[15]);
#pragma unroll
        for (int c = 0; c < 32; c++) { s[c] += y0[c]; q[c] += y0[c] * y0[c]; }
    }

    int lane = t & 63;
#pragma unroll
    for (int c = 0; c < 32; c++) {
#pragma unroll
        for (int m2 = 1; m2 < 64; m2 <<= 1) {
            s[c] += __shfl_xor(s[c], m2);
            q[c] += __shfl_xor(q[c], m2);
        }
        if (lane == c) { atomicAdd(&sl[c], s[c]); atomicAdd(&sl[32 + c], q[c]); }
    }
    __syncthreads();
    if (t < 64) atomicAdd(&stats0[t], sl[t]);
}

// ---------------------------------------------------------------- BN finalize
__global__ void k_bnfin(const float* __restrict__ stats, const int* __restrict__ np,
                        const float* __restrict__ g, const float* __restrict__ b,
                        float* __restrict__ sb, int C)
{
    int c = blockIdx.x * blockDim.x + threadIdx.x;
    if (c >= C) return;
    float n   = (float)(*np);
    float mu  = stats[c] / n;
    float var = stats[C + c] / n - mu * mu;
    float s   = g[c] / sqrtf(var + 1e-3f);
    sb[c]     = s;
    sb[C + c] = b[c] - mu * s;
}

// ---------------------------------------------------------------- k8: BN0 apply (writeback) + voxel max -> xmaxV
__global__ __launch_bounds__(256)
void k8_xmax(uint16_t* __restrict__ XpL, const int* __restrict__ vOff,
             const int* __restrict__ vCnt, const float* __restrict__ sb0,
             uint32_t* __restrict__ xmaxV, int V)
{
    int t = threadIdx.x;
    int g = blockIdx.x * 4 + (t >> 6);
    if (g >= V) return;
    int lane = t & 63;
    int c2 = lane & 15, h = lane >> 4;   // c2: u32 pair of channels, h: row phase
    int ch0 = c2 * 2;
    float sA = sb0[ch0],     bA = sb0[32 + ch0];
    float sB = sb0[ch0 + 1], bB = sb0[33 + ch0];
    int off = vOff[g], n = vCnt[g];
    float m0 = 0.0f, m1 = 0.0f;          // relu >= 0
    for (int i = h; i < n; i += 4) {
        uint32_t* ap = (uint32_t*)(XpL + (size_t)(off + i) * 32 + ch0);
        uint32_t u = *ap;
        float e0 = fmaxf(b2f((uint16_t)u) * sA + bA, 0.0f);
        float e1 = fmaxf(b2f((uint16_t)(u >> 16)) * sB + bB, 0.0f);
        *ap = (uint32_t)f2b(e0) | ((uint32_t)f2b(e1) << 16);
        m0 = fmaxf(m0, e0);
        m1 = fmaxf(m1, e1);
    }
    m0 = fmaxf(m0, __shfl_xor(m0, 16)); m0 = fmaxf(m0, __shfl_xor(m0, 32));
    m1 = fmaxf(m1, __shfl_xor(m1, 16)); m1 = fmaxf(m1, __shfl_xor(m1, 32));
    if (h == 0)
        xmaxV[(size_t)g * 16 + c2] = (uint32_t)f2b(m0) | ((uint32_t)f2b(m1) << 16);
}

// ---------------------------------------------------------------- W frags: bf16 hi/lo split of w1
__device__ __forceinline__ void load_wsplit(const float* __restrict__ w1, int cb,
                                            int l15, int lg, bf16x8* Bhi, bf16x8* Blo)
{
    int col = cb + l15;
    int kr  = lg * 8;
#pragma unroll
    for (int nb = 0; nb < 4; nb++) {
#pragma unroll
        for (int ks = 0; ks < 2; ks++) {
            U8 h, l;
#pragma unroll
            for (int jj = 0; jj < 8; jj++) {
                float w = w1[(ks * 32 + kr + jj) * 128 + col + nb * 16];
                uint16_t hb = f2b(w);
                h.u[jj] = hb;
                l.u[jj] = f2b(w - b2f(hb));
            }
            Bhi[nb * 2 + ks] = h.b;
            Blo[nb * 2 + ks] = l.b;
        }
    }
}

// ---------------------------------------------------------------- frag fetch: UNCONDITIONAL (pad rows -> zeros)
__device__ __forceinline__ void load_afrags(const uint16_t* __restrict__ XpL,
                                            const uint16_t* __restrict__ xmaxV,
                                            const int* __restrict__ vS,
                                            int tb, int rowSel, int l15, int lg,
                                            int V, U8* aL, U8* aU)
{
#pragma unroll
    for (int m = 0; m < 2; m++) {
        int r = tb + rowSel * 32 + m * 16 + l15;
        int v = vS[r];
        int vC = (v < 0) ? V : v;        // branch-free: row V of xmaxV is zeros
        aL[m].u = *(const u16x8*)(XpL + (size_t)r * 32 + lg * 8);   // pad rows: zeros (k5)
        aU[m].u = *(const u16x8*)(xmaxV + (size_t)vC * 32 + lg * 8);
    }
}

// ---------------------------------------------------------------- kA: streaming stats GEMM (no barriers in loop)
__global__ __launch_bounds__(256)
void kA_stats(const uint16_t* __restrict__ XpL, const uint16_t* __restrict__ xmaxV,
              const float* __restrict__ w1, const int* __restrict__ vS,
              const int* __restrict__ np, float* __restrict__ sPart, int nwin2, int V)
{
    __shared__ float fl[512];
    int t = threadIdx.x;
    int wv = t >> 6, lane = t & 63;
    int l15 = lane & 15, lg = lane >> 4;
    int rowSel = wv & 1, cb = (wv >> 1) * 64;

    bf16x8 Bhi[8], Blo[8];
    load_wsplit(w1, cb, l15, lg, Bhi, Blo);

    int nv = *np;
    float s[4] = {0.f, 0.f, 0.f, 0.f}, q[4] = {0.f, 0.f, 0.f, 0.f};

    for (int win = blockIdx.x; win < nwin2; win += gridDim.x) {
        int wb = win * 128;
        if (wb >= nv) break;
#pragma unroll
        for (int sub = 0; sub < 2; sub++) {
            int tb = wb + sub * 64;
            U8 aL[2], aU[2];
            load_afrags(XpL, xmaxV, vS, tb, rowSel, l15, lg, V, aL, aU);
            f32x4 acc[2][4];
#pragma unroll
            for (int m = 0; m < 2; m++)
#pragma unroll
                for (int nb = 0; nb < 4; nb++)
                    acc[m][nb] = (f32x4){0.f, 0.f, 0.f, 0.f};
#pragma unroll
            for (int m = 0; m < 2; m++)
#pragma unroll
                for (int nb = 0; nb < 4; nb++) {
                    acc[m][nb] = mfma16(aL[m].b, Bhi[nb * 2],     acc[m][nb]);
                    acc[m][nb] = mfma16(aL[m].b, Blo[nb * 2],     acc[m][nb]);
                    acc[m][nb] = mfma16(aU[m].b, Bhi[nb * 2 + 1], acc[m][nb]);
                    acc[m][nb] = mfma16(aU[m].b, Blo[nb * 2 + 1], acc[m][nb]);
                }
#pragma unroll
            for (int m = 0; m < 2; m++)
#pragma unroll
                for (int nb = 0; nb < 4; nb++)
#pragma unroll
                    for (int r = 0; r < 4; r++) {
                        float y = acc[m][nb][r];
                        s[nb] += y; q[nb] += y * y;
                    }
        }
    }
#pragma unroll
    for (int nb = 0; nb < 4; nb++) {
        s[nb] += __shfl_xor(s[nb], 16); s[nb] += __shfl_xor(s[nb], 32);
        q[nb] += __shfl_xor(q[nb], 16); q[nb] += __shfl_xor(q[nb], 32);
    }
    if (lane < 16) {
#pragma unroll
        for (int nb = 0; nb < 4; nb++) {
            int ch = cb + nb * 16 + lane;
            fl[rowSel * 128 + ch]       = s[nb];
            fl[256 + rowSel * 128 + ch] = q[nb];
        }
    }
    __syncthreads();
    if (t < 128)
        sPart[(size_t)t * NBA + blockIdx.x] = fl[t] + fl[128 + t];
    else {
        int ch = t - 128;
        sPart[(size_t)(128 + ch) * NBA + blockIdx.x] = fl[256 + ch] + fl[384 + ch];
    }
}

// ---------------------------------------------------------------- reduce stat partials
__global__ void k_red1(const float* __restrict__ part, float* __restrict__ stats1)
{
    __shared__ float red[4];
    int o = blockIdx.x, t = threadIdx.x;
    float s = 0.0f;
    for (int k = t; k < NBA; k += 256) s += part[(size_t)o * NBA + k];
#pragma unroll
    for (int m = 1; m < 64; m <<= 1) s += __shfl_xor(s, m);
    if ((t & 63) == 0) red[t >> 6] = s;
    __syncthreads();
    if (t == 0) stats1[o] = red[0] + red[1] + red[2] + red[3];
}

// ---------------------------------------------------------------- kB: MFMA GEMM + BN1 + ReLU + voxel gather-max (final)
__global__ __launch_bounds__(256)
void kB_mapply(const uint16_t* __restrict__ XpL, const uint16_t* __restrict__ xmaxV,
               const float* __restrict__ w1, const int* __restrict__ vS,
               const int* __restrict__ vOff, const int* __restrict__ vCnt,
               const int* __restrict__ np, const float* __restrict__ sb1,
               float* __restrict__ outF, int ntiles, int V)
{
    __shared__ uint16_t els[64 * ELS2];  // final relu(bn1(y)) bf16, stride 132
    int t = threadIdx.x;
    int wv = t >> 6, lane = t & 63;
    int l15 = lane & 15, lg = lane >> 4;
    int rowSel = wv & 1, cb = (wv >> 1) * 64;

    bf16x8 Bhi[8], Blo[8];
    load_wsplit(w1, cb, l15, lg, Bhi, Blo);

    float sc[4], bc[4];
#pragma unroll
    for (int nb = 0; nb < 4; nb++) {
        int c = cb + nb * 16 + l15;
        sc[nb] = sb1[c];
        bc[nb] = sb1[128 + c];
    }

    int nv = *np;
    int cg = t & 127, slot = t >> 7;

    // prologue: load tile 0's fragments
    U8 pL[2], pU[2];
    int tile = blockIdx.x;
    if (tile < ntiles && tile * 64 < nv)
        load_afrags(XpL, xmaxV, vS, tile * 64, rowSel, l15, lg, V, pL, pU);

    for (; tile < ntiles; tile += gridDim.x) {
        int tb = tile * 64;
        if (tb >= nv) break;             // uniform across block
        f32x4 acc[2][4];
#pragma unroll
        for (int m = 0; m < 2; m++)
#pragma unroll
            for (int nb = 0; nb < 4; nb++)
                acc[m][nb] = (f32x4){0.f, 0.f, 0.f, 0.f};
#pragma unroll
        for (int m = 0; m < 2; m++)
#pragma unroll
            for (int nb = 0; nb < 4; nb++) {
                acc[m][nb] = mfma16(pL[m].b, Bhi[nb * 2],     acc[m][nb]);
                acc[m][nb] = mfma16(pL[m].b, Blo[nb * 2],     acc[m][nb]);
                acc[m][nb] = mfma16(pU[m].b, Bhi[nb * 2 + 1], acc[m][nb]);
                acc[m][nb] = mfma16(pU[m].b, Blo[nb * 2 + 1], acc[m][nb]);
            }
        __syncthreads();                 // B1: prev tile's gather readers done
#pragma unroll
        for (int m = 0; m < 2; m++) {
            int rloc = rowSel * 32 + m * 16 + lg * 4;
#pragma unroll
            for (int nb = 0; nb < 4; nb++) {
                int c = cb + nb * 16 + l15;
#pragma unroll
                for (int r = 0; r < 4; r++) {
                    float e = fmaxf(acc[m][nb][r] * sc[nb] + bc[nb], 0.0f);
                    els[(rloc + r) * ELS2 + c] = f2b(e);
                }
            }
        }
        __syncthreads();                 // B2: els visible
        // prefetch NEXT tile's fragments: latency hides under the gather phase
        int tn = tile + gridDim.x;
        if (tn < ntiles && tn * 64 < nv)
            load_afrags(XpL, xmaxV, vS, tn * 64, rowSel, l15, lg, V, pL, pU);
        // voxel-driven gather (points sorted by voxel)
        int lastRow = nv - 1 - tb; if (lastRow > 63) lastRow = 63;
        int gFirst = vS[tb];
        int gLast  = vS[tb + lastRow];
        for (int g = gFirst + slot; g <= gLast; g += 2) {
            int offv = vOff[g], endv = offv + vCnt[g];
            int a  = offv > tb ? offv : tb;
            int e2 = endv < tb + 64 ? endv : tb + 64;
            float mx = 0.0f;
            for (int p = a; p < e2; p++)
                mx = fmaxf(mx, b2f(els[(p - tb) * ELS2 + cg]));
            size_t oa = (size_t)g * 128 + cg;
            if (offv >= tb && endv <= tb + 64) outF[oa] = mx;            // interior
            else if (mx > 0.0f)
                atomicMax((unsigned int*)&outF[oa], __float_as_uint(mx)); // straddler
        }
    }
}

// ---------------------------------------------------------------- launch
extern "C" void kernel_launch(void* const* d_in, const int* in_sizes, int n_in,
                              void* d_out, int out_size, void* d_ws, size_t ws_size,
                              hipStream_t stream)
{
    const float* pts = (const float*)d_in[0];
    const float* w0  = (const float*)d_in[1];
    const float* g0  = (const float*)d_in[2];
    const float* b0  = (const float*)d_in[3];
    const float* w1  = (const float*)d_in[4];
    const float* g1  = (const float*)d_in[5];
    const float* b1  = (const float*)d_in[6];
    (void)g1;

    int N      = in_sizes[0] / 5;
    int V      = out_size / 132;
    int Npad   = (N + 255) & ~255;
    int ntiles = Npad / 64;
    int nwin2  = (Npad + 127) / 128;

    char* ws = (char*)d_ws;
    size_t off = 0;
    auto alloc = [&](size_t bytes) { size_t r = off; off = (off + bytes + 255) & ~(size_t)255; return r; };

    float4* pts4    = (float4*)(ws + alloc((size_t)Npad * 16));
    int*    vS      = (int*)(ws + alloc((size_t)Npad * 4));
    size_t  zOff    = off;                                   // zero block start
    int*    cnt     = (int*)(ws + alloc((size_t)M_IDS * 4));
    int*    cursor  = (int*)(ws + alloc((size_t)M_IDS * 4));
    float*  stats   = (float*)(ws + alloc(320 * 4));         // bn0: 64 | bn1: 256
    int*    np      = (int*)(ws + alloc(4));
    size_t  zBytes  = off - zOff;
    int*    bOff    = (int*)(ws + alloc((size_t)M_IDS * 4));
    int*    idxArr  = (int*)(ws + alloc((size_t)M_IDS * 4));
    int*    vOff    = (int*)(ws + alloc((size_t)M_IDS * 4));
    int*    vCnt    = (int*)(ws + alloc((size_t)M_IDS * 4));
    int*    totO    = (int*)(ws + alloc(1024 * 4));
    int*    totC    = (int*)(ws + alloc(1024 * 4));
    int*    baseO   = (int*)(ws + alloc(1024 * 4));
    int*    baseC   = (int*)(ws + alloc(1024 * 4));
    float*  sb0     = (float*)(ws + alloc(64 * 4));
    float*  sb1     = (float*)(ws + alloc(256 * 4));
    float*  sPart   = (float*)(ws + alloc((size_t)256 * NBA * 4));
    float4* meanArr = (float4*)(ws + alloc((size_t)V * 16));
    uint16_t* XpL   = (uint16_t*)(ws + alloc((size_t)Npad * 32 * 2));
    uint16_t* xmaxV = (uint16_t*)(ws + alloc((size_t)(V + 1) * 32 * 2));  // +1 zero row
    (void)ws_size;

    hipMemsetAsync(ws + zOff, 0, zBytes, stream);
    hipMemsetAsync(vS, 0xFF, (size_t)Npad * 4, stream);
    hipMemsetAsync(xmaxV, 0, (size_t)(V + 1) * 32 * 2, stream);
    hipMemsetAsync(d_out, 0, (size_t)V * 128 * 4, stream);

    int blocksN = (N + 255) / 256;
    float* outF = (float*)d_out;

    k1_count<<<blocksN, 256, 0, stream>>>(pts, cnt, N);
    k2a_tot<<<NCHUNK, CH, 0, stream>>>(cnt, totO, totC, np);
    k2b_scan<<<1, 1024, 0, stream>>>(totO, totC, baseO, baseC);
    k2c_index<<<NCHUNK, CH, 0, stream>>>(cnt, baseO, baseC, idxArr, bOff, vOff, vCnt,
                                         outF + (size_t)V * 128);
    k3_order<<<blocksN, 256, 0, stream>>>(pts, bOff, idxArr, cursor, pts4, vS, N);
    k4_mean<<<(V + 255) / 256, 256, 0, stream>>>(pts4, vOff, vCnt, meanArr, V);
    k5_y0<<<1024, 256, 0, stream>>>(pts4, w0, vS, meanArr, XpL, stats, Npad);
    k_bnfin<<<1, 32, 0, stream>>>(stats, np, g0, b0, sb0, 32);
    k8_xmax<<<(V + 3) / 4, 256, 0, stream>>>(XpL, vOff, vCnt, sb0,
                                             (uint32_t*)xmaxV, V);
    kA_stats<<<NBA, 256, 0, stream>>>(XpL, xmaxV, w1, vS, np, sPart, nwin2, V);
    k_red1<<<256, 256, 0, stream>>>(sPart, stats + 64);
    k_bnfin<<<1, 128, 0, stream>>>(stats + 64, np, g1, b1, sb1, 128);
    kB_mapply<<<NBB, 256, 0, stream>>>(XpL, xmaxV, w1, vS, vOff, vCnt, np, sb1,
                                       outF, ntiles, V);
}

// Round 7
// 608.885 us; speedup vs baseline: 1.0330x; 1.0330x over previous
//
#include <hip/hip_runtime.h>
#include <cstdint>
#include <cstddef>

// ConvVFE: voxelize -> per-voxel mean -> MLP(10->32)+BN+ReLU -> voxel max
// -> concat -> MLP(64->128)+BN+ReLU -> voxel max ; plus voxel coords.
//
// R11: R10 prefetch regressed kB 170->209us (VGPR 80->108, occ 28->22%):
// register state beats overlap in this loop -> reverted to R9 shape.
// R9 kB is VALU-issue-bound (55%): the bf16 pack/unpack (f2b on stage,
// b2f in gather) is ~45% of per-tile VALU work. Changes vs R9:
//  - kB: els LDS buffer f32 [64][132] (33KB, still 4 blocks/CU; both
//    phases 2-way banked = free). No f2b/b2f in the loop; unroll-4 gather.
//  - d_out memset (111MB) deleted: interior voxels always plain-stored by
//    their owning tile; k2c zero-inits ONLY tile-straddling voxels (~8MB).
//    Re-run safe: k2c re-zeroes every launch.
// Everything else identical to R9 (best: 595us; kB 170us).

constexpr int M_IDS  = 220000;
constexpr int CH     = 256;
constexpr int NCHUNK = (M_IDS + CH - 1) / CH;   // 860
constexpr int NBA    = 1024;                    // kA grid / stats partials
constexpr int NBB    = 2048;                    // kB grid
constexpr int ELSF   = 132;                     // els row stride (f32)

typedef __attribute__((ext_vector_type(8))) __bf16          bf16x8;
typedef __attribute__((ext_vector_type(8))) unsigned short  u16x8;
typedef __attribute__((ext_vector_type(4))) float           f32x4;

union U8 { u16x8 u; bf16x8 b; };

__device__ __forceinline__ uint16_t f2b(float f) {
    uint32_t u = __float_as_uint(f);
    u += 0x7fffu + ((u >> 16) & 1u);
    return (uint16_t)(u >> 16);
}
__device__ __forceinline__ float b2f(uint16_t h) {
    return __uint_as_float(((uint32_t)h) << 16);
}

__device__ __forceinline__ f32x4 mfma16(bf16x8 a, bf16x8 b, f32x4 c) {
    return __builtin_amdgcn_mfma_f32_16x16x32_bf16(a, b, c, 0, 0, 0);
}

// ---------------------------------------------------------------- voxel id (shared by k1/k3)
__device__ __forceinline__ int voxel_id(const float* __restrict__ p) {
    float b = p[0], x = p[1], y = p[2], z = p[3];
    float fx = floorf((x - 0.0f) / 0.32f);
    float fy = floorf((y + 40.0f) / 0.32f);
    float fz = floorf((z + 3.0f) / 4.0f);
    bool ok = (fx >= 0.0f) && (fx < 220.0f) && (fy >= 0.0f) && (fy < 250.0f) &&
              (fz >= 0.0f) && (fz < 1.0f);
    if (!ok) return -1;
    return (int)b * 55000 + (int)fx * 250 + (int)fy + (int)fz;
}

// ---------------------------------------------------------------- k1: histogram only
__global__ void k1_count(const float* __restrict__ pts, int* __restrict__ cnt, int N)
{
    int i = blockIdx.x * blockDim.x + threadIdx.x;
    if (i >= N) return;
    int m = voxel_id(pts + (size_t)i * 5);
    if (m >= 0) atomicAdd(&cnt[m], 1);
}

// ---------------------------------------------------------------- k2: two-level scans
__global__ void k2a_tot(const int* __restrict__ cnt, int* __restrict__ totO,
                        int* __restrict__ totC, int* __restrict__ np)
{
    __shared__ int so[CH], sc[CH];
    int t = threadIdx.x;
    int id = blockIdx.x * CH + t;
    int c = (id < M_IDS) ? cnt[id] : 0;
    so[t] = (c > 0) ? 1 : 0;
    sc[t] = c;
    __syncthreads();
    for (int s = CH / 2; s > 0; s >>= 1) {
        if (t < s) { so[t] += so[t + s]; sc[t] += sc[t + s]; }
        __syncthreads();
    }
    if (t == 0) { totO[blockIdx.x] = so[0]; totC[blockIdx.x] = sc[0]; atomicAdd(np, sc[0]); }
}

__global__ void k2b_scan(const int* __restrict__ totO, const int* __restrict__ totC,
                         int* __restrict__ baseO, int* __restrict__ baseC)
{
    __shared__ int a[1024], bb[1024];
    int t = threadIdx.x;
    int vo = (t < NCHUNK) ? totO[t] : 0;
    int vc = (t < NCHUNK) ? totC[t] : 0;
    a[t] = vo; bb[t] = vc;
    __syncthreads();
    for (int off = 1; off < 1024; off <<= 1) {
        int xa = (t >= off) ? a[t - off] : 0;
        int xb = (t >= off) ? bb[t - off] : 0;
        __syncthreads();
        a[t] += xa; bb[t] += xb;
        __syncthreads();
    }
    baseO[t] = a[t] - vo;   // exclusive
    baseC[t] = bb[t] - vc;
}

__global__ void k2c_index(const int* __restrict__ cnt, const int* __restrict__ baseO,
                          const int* __restrict__ baseC, int* __restrict__ idxArr,
                          int* __restrict__ bOff, int* __restrict__ vOff,
                          int* __restrict__ vCnt, float* __restrict__ outF, int V)
{
    __shared__ int a[CH], bb[CH];
    int t = threadIdx.x;
    int id = blockIdx.x * CH + t;
    int c = (id < M_IDS) ? cnt[id] : 0;
    int occ = (c > 0) ? 1 : 0;
    a[t] = occ; bb[t] = c;
    __syncthreads();
    for (int off = 1; off < CH; off <<= 1) {
        int xa = (t >= off) ? a[t - off] : 0;
        int xb = (t >= off) ? bb[t - off] : 0;
        __syncthreads();
        a[t] += xa; bb[t] += xb;
        __syncthreads();
    }
    if (id >= M_IDS) return;
    int g  = baseO[blockIdx.x] + a[t] - occ;
    int bo = baseC[blockIdx.x] + bb[t] - c;
    idxArr[id] = g;
    bOff[id]   = bo;
    if (occ) {
        vOff[g] = bo;
        vCnt[g] = c;
        float* outCoords = outF + (size_t)V * 128;
        int b2 = id / 55000;
        int rm = id % 55000;
        int cx = rm / 250;
        int cy = rm % 250;
        outCoords[(size_t)g * 4 + 0] = (float)b2;
        outCoords[(size_t)g * 4 + 1] = 0.0f;
        outCoords[(size_t)g * 4 + 2] = (float)cy;
        outCoords[(size_t)g * 4 + 3] = (float)cx;
        // zero-init ONLY tile-straddling voxels (interior ones get a plain
        // store from their owning tile in kB; out memset deleted)
        if ((bo >> 6) != ((bo + c - 1) >> 6)) {
            float4* of = (float4*)(outF + (size_t)g * 128);
            float4 z = make_float4(0.f, 0.f, 0.f, 0.f);
#pragma unroll
            for (int k = 0; k < 32; k++) of[k] = z;
        }
    }
}

// ---------------------------------------------------------------- k3: scatter point payload to sorted order
__global__ void k3_order(const float* __restrict__ pts, const int* __restrict__ bOff,
                         const int* __restrict__ idxArr, int* __restrict__ cursor,
                         float4* __restrict__ pts4, int* __restrict__ vS, int N)
{
    int i = blockIdx.x * blockDim.x + threadIdx.x;
    if (i >= N) return;
    const float* p = pts + (size_t)i * 5;
    int m = voxel_id(p);
    if (m < 0) return;
    int slot = atomicAdd(&cursor[m], 1);
    int j = bOff[m] + slot;
    pts4[j] = make_float4(p[1], p[2], p[3], p[4]);
    vS[j]   = idxArr[m];
}

// ---------------------------------------------------------------- k4: per-voxel xyz mean (contiguous)
__global__ void k4_mean(const float4* __restrict__ pts4, const int* __restrict__ vOff,
                        const int* __restrict__ vCnt, float4* __restrict__ meanArr, int V)
{
    int g = blockIdx.x * blockDim.x + threadIdx.x;
    if (g >= V) return;
    int off = vOff[g], c = vCnt[g];
    float sx = 0.0f, sy = 0.0f, sz = 0.0f;
    for (int p = 0; p < c; p++) {
        float4 q = pts4[off + p];
        sx += q.x; sy += q.y; sz += q.z;
    }
    float ic = 1.0f / (float)c;
    meanArr[g] = make_float4(sx * ic, sy * ic, sz * ic, 0.0f);
}

// ---------------------------------------------------------------- k5: y0 = feats @ w0 (raw bf16, contiguous) + BN0 stats
__global__ __launch_bounds__(256)
void k5_y0(const float4* __restrict__ pts4, const float* __restrict__ w0,
           const int* __restrict__ vS, const float4* __restrict__ meanArr,
           uint16_t* __restrict__ XpL, float* __restrict__ stats0, int Npad)
{
    __shared__ float sl[64];
    int t = threadIdx.x;
    if (t < 64) sl[t] = 0.0f;
    __syncthreads();
    float s[32], q[32];
#pragma unroll
    for (int c = 0; c < 32; c++) { s[c] = 0.0f; q[c] = 0.0f; }

    for (int j = blockIdx.x * 256 + t; j < Npad; j += gridDim.x * 256) {
        int v = vS[j];
        if (v < 0) continue;             // pad/invalid rows: never read (vS guard)
        float4 P = pts4[j];
        float4 mn = meanArr[v];
        float x = P.x, y = P.y, z = P.z, it = P.w;
        float fx = floorf(x / 0.32f);
        float fy = floorf((y + 40.0f) / 0.32f);
        float f[10];
        f[0] = x; f[1] = y; f[2] = z; f[3] = it;
        f[4] = x - mn.x; f[5] = y - mn.y; f[6] = z - mn.z;
        f[7] = x - (fx * 0.32f + 0.16f);
        f[8] = y - (fy * 0.32f - 39.84f);
        f[9] = z + 1.0f;
        float y0[32];
#pragma unroll
        for (int c = 0; c < 32; c++) y0[c] = 0.0f;
#pragma unroll
        for (int d = 0; d < 10; d++) {
            float fd = f[d];
#pragma unroll
            for (int c = 0; c < 32; c++) y0[c] += fd * w0[d * 32 + c];
        }
        uint32_t pk[16];
#pragma unroll
        for (int k = 0; k < 16; k++)
            pk[k] = (uint32_t)f2b(y0[2 * k]) | ((uint32_t)f2b(y0[2 * k + 1]) << 16);
        uint4* rp = (uint4*)(XpL + (size_t)j * 32);
        rp[0] = make_uint4(pk[0], pk[1], pk[2], pk[3]);
        rp[1] = make_uint4(pk[4], pk[5], pk[6], pk[7]);
        rp[2] = make_uint4(pk[8], pk[9], pk[10], pk[11]);
        rp[3] = make_uint4(pk[12], pk[13], pk[14], pk[15]);
#pragma unroll
        for (int c = 0; c < 32; c++) { s[c] += y0[c]; q[c] += y0[c] * y0[c]; }
    }

    int lane = t & 63;
#pragma unroll
    for (int c = 0; c < 32; c++) {
#pragma unroll
        for (int m2 = 1; m2 < 64; m2 <<= 1) {
            s[c] += __shfl_xor(s[c], m2);
            q[c] += __shfl_xor(q[c], m2);
        }
        if (lane == c) { atomicAdd(&sl[c], s[c]); atomicAdd(&sl[32 + c], q[c]); }
    }
    __syncthreads();
    if (t < 64) atomicAdd(&stats0[t], sl[t]);
}

// ---------------------------------------------------------------- BN finalize
__global__ void k_bnfin(const float* __restrict__ stats, const int* __restrict__ np,
                        const float* __restrict__ g, const float* __restrict__ b,
                        float* __restrict__ sb, int C)
{
    int c = blockIdx.x * blockDim.x + threadIdx.x;
    if (c >= C) return;
    float n   = (float)(*np);
    float mu  = stats[c] / n;
    float var = stats[C + c] / n - mu * mu;
    float s   = g[c] / sqrtf(var + 1e-3f);
    sb[c]     = s;
    sb[C + c] = b[c] - mu * s;
}

// ---------------------------------------------------------------- k8: BN0 apply (writeback) + voxel max -> xmaxV
__global__ __launch_bounds__(256)
void k8_xmax(uint16_t* __restrict__ XpL, const int* __restrict__ vOff,
             const int* __restrict__ vCnt, const float* __restrict__ sb0,
             uint32_t* __restrict__ xmaxV, int V)
{
    int t = threadIdx.x;
    int g = blockIdx.x * 4 + (t >> 6);
    if (g >= V) return;
    int lane = t & 63;
    int c2 = lane & 15, h = lane >> 4;   // c2: u32 pair of channels, h: row phase
    int ch0 = c2 * 2;
    float sA = sb0[ch0],     bA = sb0[32 + ch0];
    float sB = sb0[ch0 + 1], bB = sb0[33 + ch0];
    int off = vOff[g], n = vCnt[g];
    float m0 = 0.0f, m1 = 0.0f;          // relu >= 0
    for (int i = h; i < n; i += 4) {
        uint32_t* ap = (uint32_t*)(XpL + (size_t)(off + i) * 32 + ch0);
        uint32_t u = *ap;
        float e0 = fmaxf(b2f((uint16_t)u) * sA + bA, 0.0f);
        float e1 = fmaxf(b2f((uint16_t)(u >> 16)) * sB + bB, 0.0f);
        *ap = (uint32_t)f2b(e0) | ((uint32_t)f2b(e1) << 16);
        m0 = fmaxf(m0, e0);
        m1 = fmaxf(m1, e1);
    }
    m0 = fmaxf(m0, __shfl_xor(m0, 16)); m0 = fmaxf(m0, __shfl_xor(m0, 32));
    m1 = fmaxf(m1, __shfl_xor(m1, 16)); m1 = fmaxf(m1, __shfl_xor(m1, 32));
    if (h == 0)
        xmaxV[(size_t)g * 16 + c2] = (uint32_t)f2b(m0) | ((uint32_t)f2b(m1) << 16);
}

// ---------------------------------------------------------------- W frags: bf16 hi/lo split of w1
__device__ __forceinline__ void load_wsplit(const float* __restrict__ w1, int cb,
                                            int l15, int lg, bf16x8* Bhi, bf16x8* Blo)
{
    int col = cb + l15;
    int kr  = lg * 8;
#pragma unroll
    for (int nb = 0; nb < 4; nb++) {
#pragma unroll
        for (int ks = 0; ks < 2; ks++) {
            U8 h, l;
#pragma unroll
            for (int jj = 0; jj < 8; jj++) {
                float w = w1[(ks * 32 + kr + jj) * 128 + col + nb * 16];
                uint16_t hb = f2b(w);
                h.u[jj] = hb;
                l.u[jj] = f2b(w - b2f(hb));
            }
            Bhi[nb * 2 + ks] = h.b;
            Blo[nb * 2 + ks] = l.b;
        }
    }
}

// ---------------------------------------------------------------- frag fetch (lower from XpL, upper from xmaxV via vS)
__device__ __forceinline__ void load_afrags(const uint16_t* __restrict__ XpL,
                                            const uint16_t* __restrict__ xmaxV,
                                            const int* __restrict__ vS,
                                            int tb, int rowSel, int l15, int lg,
                                            U8* aL, U8* aU)
{
#pragma unroll
    for (int m = 0; m < 2; m++) {
        int r = tb + rowSel * 32 + m * 16 + l15;
        int v = vS[r];                   // pad rows: -1 (memset)
        if (v >= 0) {
            aL[m].u = *(const u16x8*)(XpL + (size_t)r * 32 + lg * 8);
            aU[m].u = *(const u16x8*)(xmaxV + (size_t)v * 32 + lg * 8);
        } else {
#pragma unroll
            for (int j = 0; j < 8; j++) { aL[m].u[j] = 0; aU[m].u[j] = 0; }
        }
    }
}

// ---------------------------------------------------------------- kA: streaming stats GEMM (no barriers in loop)
__global__ __launch_bounds__(256)
void kA_stats(const uint16_t* __restrict__ XpL, const uint16_t* __restrict__ xmaxV,
              const float* __restrict__ w1, const int* __restrict__ vS,
              const int* __restrict__ np, float* __restrict__ sPart, int nwin2)
{
    __shared__ float fl[512];
    int t = threadIdx.x;
    int wv = t >> 6, lane = t & 63;
    int l15 = lane & 15, lg = lane >> 4;
    int rowSel = wv & 1, cb = (wv >> 1) * 64;

    bf16x8 Bhi[8], Blo[8];
    load_wsplit(w1, cb, l15, lg, Bhi, Blo);

    int nv = *np;
    float s[4] = {0.f, 0.f, 0.f, 0.f}, q[4] = {0.f, 0.f, 0.f, 0.f};

    for (int win = blockIdx.x; win < nwin2; win += gridDim.x) {
        int wb = win * 128;
        if (wb >= nv) break;
#pragma unroll
        for (int sub = 0; sub < 2; sub++) {
            int tb = wb + sub * 64;
            U8 aL[2], aU[2];
            load_afrags(XpL, xmaxV, vS, tb, rowSel, l15, lg, aL, aU);
            f32x4 acc[2][4];
#pragma unroll
            for (int m = 0; m < 2; m++)
#pragma unroll
                for (int nb = 0; nb < 4; nb++)
                    acc[m][nb] = (f32x4){0.f, 0.f, 0.f, 0.f};
#pragma unroll
            for (int m = 0; m < 2; m++)
#pragma unroll
                for (int nb = 0; nb < 4; nb++) {
                    acc[m][nb] = mfma16(aL[m].b, Bhi[nb * 2],     acc[m][nb]);
                    acc[m][nb] = mfma16(aL[m].b, Blo[nb * 2],     acc[m][nb]);
                    acc[m][nb] = mfma16(aU[m].b, Bhi[nb * 2 + 1], acc[m][nb]);
                    acc[m][nb] = mfma16(aU[m].b, Blo[nb * 2 + 1], acc[m][nb]);
                }
#pragma unroll
            for (int m = 0; m < 2; m++)
#pragma unroll
                for (int nb = 0; nb < 4; nb++)
#pragma unroll
                    for (int r = 0; r < 4; r++) {
                        float y = acc[m][nb][r];
                        s[nb] += y; q[nb] += y * y;
                    }
        }
    }
#pragma unroll
    for (int nb = 0; nb < 4; nb++) {
        s[nb] += __shfl_xor(s[nb], 16); s[nb] += __shfl_xor(s[nb], 32);
        q[nb] += __shfl_xor(q[nb], 16); q[nb] += __shfl_xor(q[nb], 32);
    }
    if (lane < 16) {
#pragma unroll
        for (int nb = 0; nb < 4; nb++) {
            int ch = cb + nb * 16 + lane;
            fl[rowSel * 128 + ch]       = s[nb];
            fl[256 + rowSel * 128 + ch] = q[nb];
        }
    }
    __syncthreads();
    if (t < 128)
        sPart[(size_t)t * NBA + blockIdx.x] = fl[t] + fl[128 + t];
    else {
        int ch = t - 128;
        sPart[(size_t)(128 + ch) * NBA + blockIdx.x] = fl[256 + ch] + fl[384 + ch];
    }
}

// ---------------------------------------------------------------- reduce stat partials
__global__ void k_red1(const float* __restrict__ part, float* __restrict__ stats1)
{
    __shared__ float red[4];
    int o = blockIdx.x, t = threadIdx.x;
    float s = 0.0f;
    for (int k = t; k < NBA; k += 256) s += part[(size_t)o * NBA + k];
#pragma unroll
    for (int m = 1; m < 64; m <<= 1) s += __shfl_xor(s, m);
    if ((t & 63) == 0) red[t >> 6] = s;
    __syncthreads();
    if (t == 0) stats1[o] = red[0] + red[1] + red[2] + red[3];
}

// ---------------------------------------------------------------- kB: MFMA GEMM + BN1 + ReLU + voxel gather-max (final)
__global__ __launch_bounds__(256)
void kB_mapply(const uint16_t* __restrict__ XpL, const uint16_t* __restrict__ xmaxV,
               const float* __restrict__ w1, const int* __restrict__ vS,
               const int* __restrict__ vOff, const int* __restrict__ vCnt,
               const int* __restrict__ np, const float* __restrict__ sb1,
               float* __restrict__ outF, int ntiles)
{
    __shared__ float els[64 * ELSF];     // final relu(bn1(y)) f32, stride 132
    int t = threadIdx.x;
    int wv = t >> 6, lane = t & 63;
    int l15 = lane & 15, lg = lane >> 4;
    int rowSel = wv & 1, cb = (wv >> 1) * 64;

    bf16x8 Bhi[8], Blo[8];
    load_wsplit(w1, cb, l15, lg, Bhi, Blo);

    float sc[4], bc[4];
#pragma unroll
    for (int nb = 0; nb < 4; nb++) {
        int c = cb + nb * 16 + l15;
        sc[nb] = sb1[c];
        bc[nb] = sb1[128 + c];
    }

    int nv = *np;
    int cg = t & 127, slot = t >> 7;

    for (int tile = blockIdx.x; tile < ntiles; tile += gridDim.x) {
        int tb = tile * 64;
        if (tb >= nv) break;             // uniform across block
        U8 aL[2], aU[2];
        load_afrags(XpL, xmaxV, vS, tb, rowSel, l15, lg, aL, aU);
        f32x4 acc[2][4];
#pragma unroll
        for (int m = 0; m < 2; m++)
#pragma unroll
            for (int nb = 0; nb < 4; nb++)
                acc[m][nb] = (f32x4){0.f, 0.f, 0.f, 0.f};
#pragma unroll
        for (int m = 0; m < 2; m++)
#pragma unroll
            for (int nb = 0; nb < 4; nb++) {
                acc[m][nb] = mfma16(aL[m].b, Bhi[nb * 2],     acc[m][nb]);
                acc[m][nb] = mfma16(aL[m].b, Blo[nb * 2],     acc[m][nb]);
                acc[m][nb] = mfma16(aU[m].b, Bhi[nb * 2 + 1], acc[m][nb]);
                acc[m][nb] = mfma16(aU[m].b, Blo[nb * 2 + 1], acc[m][nb]);
            }
        __syncthreads();                 // B1: prev tile's gather readers done
#pragma unroll
        for (int m = 0; m < 2; m++) {
            int rloc = rowSel * 32 + m * 16 + lg * 4;
#pragma unroll
            for (int nb = 0; nb < 4; nb++) {
                int c = cb + nb * 16 + l15;
#pragma unroll
                for (int r = 0; r < 4; r++)
                    els[(rloc + r) * ELSF + c] =
                        fmaxf(acc[m][nb][r] * sc[nb] + bc[nb], 0.0f);
            }
        }
        __syncthreads();                 // B2: els visible
        // voxel-driven gather (points sorted by voxel)
        int lastRow = nv - 1 - tb; if (lastRow > 63) lastRow = 63;
        int gFirst = vS[tb];
        int gLast  = vS[tb + lastRow];
        for (int g = gFirst + slot; g <= gLast; g += 2) {
            int offv = vOff[g], endv = offv + vCnt[g];
            int a  = offv > tb ? offv : tb;
            int e2 = endv < tb + 64 ? endv : tb + 64;
            float mx = 0.0f;
#pragma unroll 4
            for (int p = a; p < e2; p++)
                mx = fmaxf(mx, els[(p - tb) * ELSF + cg]);
            size_t oa = (size_t)g * 128 + cg;
            if (offv >= tb && endv <= tb + 64) outF[oa] = mx;            // interior
            else if (mx > 0.0f)
                atomicMax((unsigned int*)&outF[oa], __float_as_uint(mx)); // straddler
        }
    }
}

// ---------------------------------------------------------------- launch
extern "C" void kernel_launch(void* const* d_in, const int* in_sizes, int n_in,
                              void* d_out, int out_size, void* d_ws, size_t ws_size,
                              hipStream_t stream)
{
    const float* pts = (const float*)d_in[0];
    const float* w0  = (const float*)d_in[1];
    const float* g0  = (const float*)d_in[2];
    const float* b0  = (const float*)d_in[3];
    const float* w1  = (const float*)d_in[4];
    const float* g1  = (const float*)d_in[5];
    const float* b1  = (const float*)d_in[6];

    int N      = in_sizes[0] / 5;
    int V      = out_size / 132;
    int Npad   = (N + 255) & ~255;
    int ntiles = Npad / 64;
    int nwin2  = (Npad + 127) / 128;

    char* ws = (char*)d_ws;
    size_t off = 0;
    auto alloc = [&](size_t bytes) { size_t r = off; off = (off + bytes + 255) & ~(size_t)255; return r; };

    float4* pts4    = (float4*)(ws + alloc((size_t)Npad * 16));
    int*    vS      = (int*)(ws + alloc((size_t)Npad * 4));
    size_t  zOff    = off;                                   // zero block start
    int*    cnt     = (int*)(ws + alloc((size_t)M_IDS * 4));
    int*    cursor  = (int*)(ws + alloc((size_t)M_IDS * 4));
    float*  stats   = (float*)(ws + alloc(320 * 4));         // bn0: 64 | bn1: 256
    int*    np      = (int*)(ws + alloc(4));
    size_t  zBytes  = off - zOff;
    int*    bOff    = (int*)(ws + alloc((size_t)M_IDS * 4));
    int*    idxArr  = (int*)(ws + alloc((size_t)M_IDS * 4));
    int*    vOff    = (int*)(ws + alloc((size_t)M_IDS * 4));
    int*    vCnt    = (int*)(ws + alloc((size_t)M_IDS * 4));
    int*    totO    = (int*)(ws + alloc(1024 * 4));
    int*    totC    = (int*)(ws + alloc(1024 * 4));
    int*    baseO   = (int*)(ws + alloc(1024 * 4));
    int*    baseC   = (int*)(ws + alloc(1024 * 4));
    float*  sb0     = (float*)(ws + alloc(64 * 4));
    float*  sb1     = (float*)(ws + alloc(256 * 4));
    float*  sPart   = (float*)(ws + alloc((size_t)256 * NBA * 4));
    float4* meanArr = (float4*)(ws + alloc((size_t)V * 16));
    uint16_t* XpL   = (uint16_t*)(ws + alloc((size_t)Npad * 32 * 2));
    uint16_t* xmaxV = (uint16_t*)(ws + alloc((size_t)V * 32 * 2));
    (void)ws_size;

    hipMemsetAsync(ws + zOff, 0, zBytes, stream);
    hipMemsetAsync(vS, 0xFF, (size_t)Npad * 4, stream);

    int blocksN = (N + 255) / 256;
    float* outF = (float*)d_out;

    k1_count<<<blocksN, 256, 0, stream>>>(pts, cnt, N);
    k2a_tot<<<NCHUNK, CH, 0, stream>>>(cnt, totO, totC, np);
    k2b_scan<<<1, 1024, 0, stream>>>(totO, totC, baseO, baseC);
    k2c_index<<<NCHUNK, CH, 0, stream>>>(cnt, baseO, baseC, idxArr, bOff, vOff, vCnt,
                                         outF, V);
    k3_order<<<blocksN, 256, 0, stream>>>(pts, bOff, idxArr, cursor, pts4, vS, N);
    k4_mean<<<(V + 255) / 256, 256, 0, stream>>>(pts4, vOff, vCnt, meanArr, V);
    k5_y0<<<1024, 256, 0, stream>>>(pts4, w0, vS, meanArr, XpL, stats, Npad);
    k_bnfin<<<1, 32, 0, stream>>>(stats, np, g0, b0, sb0, 32);
    k8_xmax<<<(V + 3) / 4, 256, 0, stream>>>(XpL, vOff, vCnt, sb0,
                                             (uint32_t*)xmaxV, V);
    kA_stats<<<NBA, 256, 0, stream>>>(XpL, xmaxV, w1, vS, np, sPart, nwin2);
    k_red1<<<256, 256, 0, stream>>>(sPart, stats + 64);
    k_bnfin<<<1, 128, 0, stream>>>(stats + 64, np, g1, b1, sb1, 128);
    kB_mapply<<<NBB, 256, 0, stream>>>(XpL, xmaxV, w1, vS, vOff, vCnt, np, sb1,
                                       outF, ntiles);
}

// Round 8
// 583.804 us; speedup vs baseline: 1.0774x; 1.0430x over previous
//
#include <hip/hip_runtime.h>
#include <cstdint>
#include <cstddef>

// ConvVFE: voxelize -> per-voxel mean -> MLP(10->32)+BN+ReLU -> voxel max
// -> concat -> MLP(64->128)+BN+ReLU -> voxel max ; plus voxel coords.
//
// R12: R11 falsified "kB is VALU-bound": removing pack/unpack dropped
// VALUBusy 55->45% but kB got SLOWER (170->196us). All barriered variants
// land 160-200us regardless of VALU/traffic/MFMA (~25/13us at roofline) ->
// the invariant cost is 15,625 tiles x 2 __syncthreads with full waitcnt
// drains (block lockstep). This round: ZERO-barrier kB. Wave wv owns rows
// [tb+rowSel*32,+32) x channels [cb,cb+64) (the partition it already
// computes), stages its 32x64 f32 block to a WAVE-PRIVATE LDS slice
// (els[wv][32*66], 33.8KB, <=2-way banks), gathers within the wave
// (lane l = channel cb+l). ds_write->ds_read ordering is wave-local.
// Interior-ness is per-32-row window: k2c straddler zero-init >>6 -> >>5.
// Everything else identical to R11 (which = R9 + f32 els + no-out-memset).

constexpr int M_IDS  = 220000;
constexpr int CH     = 256;
constexpr int NCHUNK = (M_IDS + CH - 1) / CH;   // 860
constexpr int NBA    = 1024;                    // kA grid / stats partials
constexpr int NBB    = 2048;                    // kB grid
constexpr int EWS    = 66;                      // wave-private els row stride (f32)

typedef __attribute__((ext_vector_type(8))) __bf16          bf16x8;
typedef __attribute__((ext_vector_type(8))) unsigned short  u16x8;
typedef __attribute__((ext_vector_type(4))) float           f32x4;

union U8 { u16x8 u; bf16x8 b; };

__device__ __forceinline__ uint16_t f2b(float f) {
    uint32_t u = __float_as_uint(f);
    u += 0x7fffu + ((u >> 16) & 1u);
    return (uint16_t)(u >> 16);
}
__device__ __forceinline__ float b2f(uint16_t h) {
    return __uint_as_float(((uint32_t)h) << 16);
}

__device__ __forceinline__ f32x4 mfma16(bf16x8 a, bf16x8 b, f32x4 c) {
    return __builtin_amdgcn_mfma_f32_16x16x32_bf16(a, b, c, 0, 0, 0);
}

// ---------------------------------------------------------------- voxel id (shared by k1/k3)
__device__ __forceinline__ int voxel_id(const float* __restrict__ p) {
    float b = p[0], x = p[1], y = p[2], z = p[3];
    float fx = floorf((x - 0.0f) / 0.32f);
    float fy = floorf((y + 40.0f) / 0.32f);
    float fz = floorf((z + 3.0f) / 4.0f);
    bool ok = (fx >= 0.0f) && (fx < 220.0f) && (fy >= 0.0f) && (fy < 250.0f) &&
              (fz >= 0.0f) && (fz < 1.0f);
    if (!ok) return -1;
    return (int)b * 55000 + (int)fx * 250 + (int)fy + (int)fz;
}

// ---------------------------------------------------------------- k1: histogram only
__global__ void k1_count(const float* __restrict__ pts, int* __restrict__ cnt, int N)
{
    int i = blockIdx.x * blockDim.x + threadIdx.x;
    if (i >= N) return;
    int m = voxel_id(pts + (size_t)i * 5);
    if (m >= 0) atomicAdd(&cnt[m], 1);
}

// ---------------------------------------------------------------- k2: two-level scans
__global__ void k2a_tot(const int* __restrict__ cnt, int* __restrict__ totO,
                        int* __restrict__ totC, int* __restrict__ np)
{
    __shared__ int so[CH], sc[CH];
    int t = threadIdx.x;
    int id = blockIdx.x * CH + t;
    int c = (id < M_IDS) ? cnt[id] : 0;
    so[t] = (c > 0) ? 1 : 0;
    sc[t] = c;
    __syncthreads();
    for (int s = CH / 2; s > 0; s >>= 1) {
        if (t < s) { so[t] += so[t + s]; sc[t] += sc[t + s]; }
        __syncthreads();
    }
    if (t == 0) { totO[blockIdx.x] = so[0]; totC[blockIdx.x] = sc[0]; atomicAdd(np, sc[0]); }
}

__global__ void k2b_scan(const int* __restrict__ totO, const int* __restrict__ totC,
                         int* __restrict__ baseO, int* __restrict__ baseC)
{
    __shared__ int a[1024], bb[1024];
    int t = threadIdx.x;
    int vo = (t < NCHUNK) ? totO[t] : 0;
    int vc = (t < NCHUNK) ? totC[t] : 0;
    a[t] = vo; bb[t] = vc;
    __syncthreads();
    for (int off = 1; off < 1024; off <<= 1) {
        int xa = (t >= off) ? a[t - off] : 0;
        int xb = (t >= off) ? bb[t - off] : 0;
        __syncthreads();
        a[t] += xa; bb[t] += xb;
        __syncthreads();
    }
    baseO[t] = a[t] - vo;   // exclusive
    baseC[t] = bb[t] - vc;
}

__global__ void k2c_index(const int* __restrict__ cnt, const int* __restrict__ baseO,
                          const int* __restrict__ baseC, int* __restrict__ idxArr,
                          int* __restrict__ bOff, int* __restrict__ vOff,
                          int* __restrict__ vCnt, float* __restrict__ outF, int V)
{
    __shared__ int a[CH], bb[CH];
    int t = threadIdx.x;
    int id = blockIdx.x * CH + t;
    int c = (id < M_IDS) ? cnt[id] : 0;
    int occ = (c > 0) ? 1 : 0;
    a[t] = occ; bb[t] = c;
    __syncthreads();
    for (int off = 1; off < CH; off <<= 1) {
        int xa = (t >= off) ? a[t - off] : 0;
        int xb = (t >= off) ? bb[t - off] : 0;
        __syncthreads();
        a[t] += xa; bb[t] += xb;
        __syncthreads();
    }
    if (id >= M_IDS) return;
    int g  = baseO[blockIdx.x] + a[t] - occ;
    int bo = baseC[blockIdx.x] + bb[t] - c;
    idxArr[id] = g;
    bOff[id]   = bo;
    if (occ) {
        vOff[g] = bo;
        vCnt[g] = c;
        float* outCoords = outF + (size_t)V * 128;
        int b2 = id / 55000;
        int rm = id % 55000;
        int cx = rm / 250;
        int cy = rm % 250;
        outCoords[(size_t)g * 4 + 0] = (float)b2;
        outCoords[(size_t)g * 4 + 1] = 0.0f;
        outCoords[(size_t)g * 4 + 2] = (float)cy;
        outCoords[(size_t)g * 4 + 3] = (float)cx;
        // zero-init ONLY voxels straddling a 32-row window (interior ones get
        // a plain store from their owning wave in kB; out memset deleted)
        if ((bo >> 5) != ((bo + c - 1) >> 5)) {
            float4* of = (float4*)(outF + (size_t)g * 128);
            float4 z = make_float4(0.f, 0.f, 0.f, 0.f);
#pragma unroll
            for (int k = 0; k < 32; k++) of[k] = z;
        }
    }
}

// ---------------------------------------------------------------- k3: scatter point payload to sorted order
__global__ void k3_order(const float* __restrict__ pts, const int* __restrict__ bOff,
                         const int* __restrict__ idxArr, int* __restrict__ cursor,
                         float4* __restrict__ pts4, int* __restrict__ vS, int N)
{
    int i = blockIdx.x * blockDim.x + threadIdx.x;
    if (i >= N) return;
    const float* p = pts + (size_t)i * 5;
    int m = voxel_id(p);
    if (m < 0) return;
    int slot = atomicAdd(&cursor[m], 1);
    int j = bOff[m] + slot;
    pts4[j] = make_float4(p[1], p[2], p[3], p[4]);
    vS[j]   = idxArr[m];
}

// ---------------------------------------------------------------- k4: per-voxel xyz mean (contiguous)
__global__ void k4_mean(const float4* __restrict__ pts4, const int* __restrict__ vOff,
                        const int* __restrict__ vCnt, float4* __restrict__ meanArr, int V)
{
    int g = blockIdx.x * blockDim.x + threadIdx.x;
    if (g >= V) return;
    int off = vOff[g], c = vCnt[g];
    float sx = 0.0f, sy = 0.0f, sz = 0.0f;
    for (int p = 0; p < c; p++) {
        float4 q = pts4[off + p];
        sx += q.x; sy += q.y; sz += q.z;
    }
    float ic = 1.0f / (float)c;
    meanArr[g] = make_float4(sx * ic, sy * ic, sz * ic, 0.0f);
}

// ---------------------------------------------------------------- k5: y0 = feats @ w0 (raw bf16, contiguous) + BN0 stats
__global__ __launch_bounds__(256)
void k5_y0(const float4* __restrict__ pts4, const float* __restrict__ w0,
           const int* __restrict__ vS, const float4* __restrict__ meanArr,
           uint16_t* __restrict__ XpL, float* __restrict__ stats0, int Npad)
{
    __shared__ float sl[64];
    int t = threadIdx.x;
    if (t < 64) sl[t] = 0.0f;
    __syncthreads();
    float s[32], q[32];
#pragma unroll
    for (int c = 0; c < 32; c++) { s[c] = 0.0f; q[c] = 0.0f; }

    for (int j = blockIdx.x * 256 + t; j < Npad; j += gridDim.x * 256) {
        int v = vS[j];
        if (v < 0) continue;             // pad/invalid rows: never read (vS guard)
        float4 P = pts4[j];
        float4 mn = meanArr[v];
        float x = P.x, y = P.y, z = P.z, it = P.w;
        float fx = floorf(x / 0.32f);
        float fy = floorf((y + 40.0f) / 0.32f);
        float f[10];
        f[0] = x; f[1] = y; f[2] = z; f[3] = it;
        f[4] = x - mn.x; f[5] = y - mn.y; f[6] = z - mn.z;
        f[7] = x - (fx * 0.32f + 0.16f);
        f[8] = y - (fy * 0.32f - 39.84f);
        f[9] = z + 1.0f;
        float y0[32];
#pragma unroll
        for (int c = 0; c < 32; c++) y0[c] = 0.0f;
#pragma unroll
        for (int d = 0; d < 10; d++) {
            float fd = f[d];
#pragma unroll
            for (int c = 0; c < 32; c++) y0[c] += fd * w0[d * 32 + c];
        }
        uint32_t pk[16];
#pragma unroll
        for (int k = 0; k < 16; k++)
            pk[k] = (uint32_t)f2b(y0[2 * k]) | ((uint32_t)f2b(y0[2 * k + 1]) << 16);
        uint4* rp = (uint4*)(XpL + (size_t)j * 32);
        rp[0] = make_uint4(pk[0], pk[1], pk[2], pk[3]);
        rp[1] = make_uint4(pk[4], pk[5], pk[6], pk[7]);
        rp[2] = make_uint4(pk[8], pk[9], pk[10], pk[11]);
        rp[3] = make_uint4(pk[12], pk[13], pk[14], pk[15]);
#pragma unroll
        for (int c = 0; c < 32; c++) { s[c] += y0[c]; q[c] += y0[c] * y0[c]; }
    }

    int lane = t & 63;
#pragma unroll
    for (int c = 0; c < 32; c++) {
#pragma unroll
        for (int m2 = 1; m2 < 64; m2 <<= 1) {
            s[c] += __shfl_xor(s[c], m2);
            q[c] += __shfl_xor(q[c], m2);
        }
        if (lane == c) { atomicAdd(&sl[c], s[c]); atomicAdd(&sl[32 + c], q[c]); }
    }
    __syncthreads();
    if (t < 64) atomicAdd(&stats0[t], sl[t]);
}

// ---------------------------------------------------------------- BN finalize
__global__ void k_bnfin(const float* __restrict__ stats, const int* __restrict__ np,
                        const float* __restrict__ g, const float* __restrict__ b,
                        float* __restrict__ sb, int C)
{
    int c = blockIdx.x * blockDim.x + threadIdx.x;
    if (c >= C) return;
    float n   = (float)(*np);
    float mu  = stats[c] / n;
    float var = stats[C + c] / n - mu * mu;
    float s   = g[c] / sqrtf(var + 1e-3f);
    sb[c]     = s;
    sb[C + c] = b[c] - mu * s;
}

// ---------------------------------------------------------------- k8: BN0 apply (writeback) + voxel max -> xmaxV
__global__ __launch_bounds__(256)
void k8_xmax(uint16_t* __restrict__ XpL, const int* __restrict__ vOff,
             const int* __restrict__ vCnt, const float* __restrict__ sb0,
             uint32_t* __restrict__ xmaxV, int V)
{
    int t = threadIdx.x;
    int g = blockIdx.x * 4 + (t >> 6);
    if (g >= V) return;
    int lane = t & 63;
    int c2 = lane & 15, h = lane >> 4;   // c2: u32 pair of channels, h: row phase
    int ch0 = c2 * 2;
    float sA = sb0[ch0],     bA = sb0[32 + ch0];
    float sB = sb0[ch0 + 1], bB = sb0[33 + ch0];
    int off = vOff[g], n = vCnt[g];
    float m0 = 0.0f, m1 = 0.0f;          // relu >= 0
    for (int i = h; i < n; i += 4) {
        uint32_t* ap = (uint32_t*)(XpL + (size_t)(off + i) * 32 + ch0);
        uint32_t u = *ap;
        float e0 = fmaxf(b2f((uint16_t)u) * sA + bA, 0.0f);
        float e1 = fmaxf(b2f((uint16_t)(u >> 16)) * sB + bB, 0.0f);
        *ap = (uint32_t)f2b(e0) | ((uint32_t)f2b(e1) << 16);
        m0 = fmaxf(m0, e0);
        m1 = fmaxf(m1, e1);
    }
    m0 = fmaxf(m0, __shfl_xor(m0, 16)); m0 = fmaxf(m0, __shfl_xor(m0, 32));
    m1 = fmaxf(m1, __shfl_xor(m1, 16)); m1 = fmaxf(m1, __shfl_xor(m1, 32));
    if (h == 0)
        xmaxV[(size_t)g * 16 + c2] = (uint32_t)f2b(m0) | ((uint32_t)f2b(m1) << 16);
}

// ---------------------------------------------------------------- W frags: bf16 hi/lo split of w1
__device__ __forceinline__ void load_wsplit(const float* __restrict__ w1, int cb,
                                            int l15, int lg, bf16x8* Bhi, bf16x8* Blo)
{
    int col = cb + l15;
    int kr  = lg * 8;
#pragma unroll
    for (int nb = 0; nb < 4; nb++) {
#pragma unroll
        for (int ks = 0; ks < 2; ks++) {
            U8 h, l;
#pragma unroll
            for (int jj = 0; jj < 8; jj++) {
                float w = w1[(ks * 32 + kr + jj) * 128 + col + nb * 16];
                uint16_t hb = f2b(w);
                h.u[jj] = hb;
                l.u[jj] = f2b(w - b2f(hb));
            }
            Bhi[nb * 2 + ks] = h.b;
            Blo[nb * 2 + ks] = l.b;
        }
    }
}

// ---------------------------------------------------------------- frag fetch (lower from XpL, upper from xmaxV via vS)
__device__ __forceinline__ void load_afrags(const uint16_t* __restrict__ XpL,
                                            const uint16_t* __restrict__ xmaxV,
                                            const int* __restrict__ vS,
                                            int tb, int rowSel, int l15, int lg,
                                            U8* aL, U8* aU)
{
#pragma unroll
    for (int m = 0; m < 2; m++) {
        int r = tb + rowSel * 32 + m * 16 + l15;
        int v = vS[r];                   // pad rows: -1 (memset)
        if (v >= 0) {
            aL[m].u = *(const u16x8*)(XpL + (size_t)r * 32 + lg * 8);
            aU[m].u = *(const u16x8*)(xmaxV + (size_t)v * 32 + lg * 8);
        } else {
#pragma unroll
            for (int j = 0; j < 8; j++) { aL[m].u[j] = 0; aU[m].u[j] = 0; }
        }
    }
}

// ---------------------------------------------------------------- kA: streaming stats GEMM (no barriers in loop)
__global__ __launch_bounds__(256)
void kA_stats(const uint16_t* __restrict__ XpL, const uint16_t* __restrict__ xmaxV,
              const float* __restrict__ w1, const int* __restrict__ vS,
              const int* __restrict__ np, float* __restrict__ sPart, int nwin2)
{
    __shared__ float fl[512];
    int t = threadIdx.x;
    int wv = t >> 6, lane = t & 63;
    int l15 = lane & 15, lg = lane >> 4;
    int rowSel = wv & 1, cb = (wv >> 1) * 64;

    bf16x8 Bhi[8], Blo[8];
    load_wsplit(w1, cb, l15, lg, Bhi, Blo);

    int nv = *np;
    float s[4] = {0.f, 0.f, 0.f, 0.f}, q[4] = {0.f, 0.f, 0.f, 0.f};

    for (int win = blockIdx.x; win < nwin2; win += gridDim.x) {
        int wb = win * 128;
        if (wb >= nv) break;
#pragma unroll
        for (int sub = 0; sub < 2; sub++) {
            int tb = wb + sub * 64;
            U8 aL[2], aU[2];
            load_afrags(XpL, xmaxV, vS, tb, rowSel, l15, lg, aL, aU);
            f32x4 acc[2][4];
#pragma unroll
            for (int m = 0; m < 2; m++)
#pragma unroll
                for (int nb = 0; nb < 4; nb++)
                    acc[m][nb] = (f32x4){0.f, 0.f, 0.f, 0.f};
#pragma unroll
            for (int m = 0; m < 2; m++)
#pragma unroll
                for (int nb = 0; nb < 4; nb++) {
                    acc[m][nb] = mfma16(aL[m].b, Bhi[nb * 2],     acc[m][nb]);
                    acc[m][nb] = mfma16(aL[m].b, Blo[nb * 2],     acc[m][nb]);
                    acc[m][nb] = mfma16(aU[m].b, Bhi[nb * 2 + 1], acc[m][nb]);
                    acc[m][nb] = mfma16(aU[m].b, Blo[nb * 2 + 1], acc[m][nb]);
                }
#pragma unroll
            for (int m = 0; m < 2; m++)
#pragma unroll
                for (int nb = 0; nb < 4; nb++)
#pragma unroll
                    for (int r = 0; r < 4; r++) {
                        float y = acc[m][nb][r];
                        s[nb] += y; q[nb] += y * y;
                    }
        }
    }
#pragma unroll
    for (int nb = 0; nb < 4; nb++) {
        s[nb] += __shfl_xor(s[nb], 16); s[nb] += __shfl_xor(s[nb], 32);
        q[nb] += __shfl_xor(q[nb], 16); q[nb] += __shfl_xor(q[nb], 32);
    }
    if (lane < 16) {
#pragma unroll
        for (int nb = 0; nb < 4; nb++) {
            int ch = cb + nb * 16 + lane;
            fl[rowSel * 128 + ch]       = s[nb];
            fl[256 + rowSel * 128 + ch] = q[nb];
        }
    }
    __syncthreads();
    if (t < 128)
        sPart[(size_t)t * NBA + blockIdx.x] = fl[t] + fl[128 + t];
    else {
        int ch = t - 128;
        sPart[(size_t)(128 + ch) * NBA + blockIdx.x] = fl[256 + ch] + fl[384 + ch];
    }
}

// ---------------------------------------------------------------- reduce stat partials
__global__ void k_red1(const float* __restrict__ part, float* __restrict__ stats1)
{
    __shared__ float red[4];
    int o = blockIdx.x, t = threadIdx.x;
    float s = 0.0f;
    for (int k = t; k < NBA; k += 256) s += part[(size_t)o * NBA + k];
#pragma unroll
    for (int m = 1; m < 64; m <<= 1) s += __shfl_xor(s, m);
    if ((t & 63) == 0) red[t >> 6] = s;
    __syncthreads();
    if (t == 0) stats1[o] = red[0] + red[1] + red[2] + red[3];
}

// ---------------------------------------------------------------- kB: MFMA GEMM + BN1 + ReLU + voxel gather-max
//      ZERO barriers: wave-private stage + gather (wave owns 32 rows x 64 ch)
__global__ __launch_bounds__(256)
void kB_mapply(const uint16_t* __restrict__ XpL, const uint16_t* __restrict__ xmaxV,
               const float* __restrict__ w1, const int* __restrict__ vS,
               const int* __restrict__ vOff, const int* __restrict__ vCnt,
               const int* __restrict__ np, const float* __restrict__ sb1,
               float* __restrict__ outF, int ntiles)
{
    __shared__ float els[4][32 * EWS];   // wave-private f32 stage (33.8KB)
    int t = threadIdx.x;
    int wv = t >> 6, lane = t & 63;
    int l15 = lane & 15, lg = lane >> 4;
    int rowSel = wv & 1, cb = (wv >> 1) * 64;
    float* ew = els[wv];

    bf16x8 Bhi[8], Blo[8];
    load_wsplit(w1, cb, l15, lg, Bhi, Blo);

    float sc[4], bc[4];
#pragma unroll
    for (int nb = 0; nb < 4; nb++) {
        int c = cb + nb * 16 + l15;
        sc[nb] = sb1[c];
        bc[nb] = sb1[128 + c];
    }

    int nv = *np;

    for (int tile = blockIdx.x; tile < ntiles; tile += gridDim.x) {
        int tb = tile * 64;
        if (tb >= nv) break;             // uniform across block
        int tw = tb + rowSel * 32;       // this wave's 32-row window
        if (tw >= nv) continue;          // wave-uniform: window fully padded
        U8 aL[2], aU[2];
        load_afrags(XpL, xmaxV, vS, tb, rowSel, l15, lg, aL, aU);
        f32x4 acc[2][4];
#pragma unroll
        for (int m = 0; m < 2; m++)
#pragma unroll
            for (int nb = 0; nb < 4; nb++)
                acc[m][nb] = (f32x4){0.f, 0.f, 0.f, 0.f};
#pragma unroll
        for (int m = 0; m < 2; m++)
#pragma unroll
            for (int nb = 0; nb < 4; nb++) {
                acc[m][nb] = mfma16(aL[m].b, Bhi[nb * 2],     acc[m][nb]);
                acc[m][nb] = mfma16(aL[m].b, Blo[nb * 2],     acc[m][nb]);
                acc[m][nb] = mfma16(aU[m].b, Bhi[nb * 2 + 1], acc[m][nb]);
                acc[m][nb] = mfma16(aU[m].b, Blo[nb * 2 + 1], acc[m][nb]);
            }
        // stage BN1+ReLU result to the wave's PRIVATE slice (no barrier;
        // ds_write->ds_read ordering is wave-local, compiler inserts waits)
#pragma unroll
        for (int m = 0; m < 2; m++) {
            int rloc = m * 16 + lg * 4;  // 0..31 within the window
#pragma unroll
            for (int nb = 0; nb < 4; nb++) {
                int ci = nb * 16 + l15;  // 0..63 within the wave's channels
#pragma unroll
                for (int r = 0; r < 4; r++)
                    ew[(rloc + r) * EWS + ci] =
                        fmaxf(acc[m][nb][r] * sc[nb] + bc[nb], 0.0f);
            }
        }
        // gather: lane l owns channel cb+l over this wave's 32-row window
        int lastRow = nv - 1 - tw; if (lastRow > 31) lastRow = 31;
        int gFirst = vS[tw];
        int gLast  = vS[tw + lastRow];
        for (int g = gFirst; g <= gLast; g++) {
            int offv = vOff[g], endv = offv + vCnt[g];
            int a  = offv > tw ? offv : tw;
            int e2 = endv < tw + 32 ? endv : tw + 32;
            float mx = 0.0f;
            for (int p = a; p < e2; p++)
                mx = fmaxf(mx, ew[(p - tw) * EWS + lane]);
            size_t oa = (size_t)g * 128 + cb + lane;
            if (offv >= tw && endv <= tw + 32) outF[oa] = mx;            // window-interior
            else if (mx > 0.0f)
                atomicMax((unsigned int*)&outF[oa], __float_as_uint(mx)); // straddler
        }
    }
}

// ---------------------------------------------------------------- launch
extern "C" void kernel_launch(void* const* d_in, const int* in_sizes, int n_in,
                              void* d_out, int out_size, void* d_ws, size_t ws_size,
                              hipStream_t stream)
{
    const float* pts = (const float*)d_in[0];
    const float* w0  = (const float*)d_in[1];
    const float* g0  = (const float*)d_in[2];
    const float* b0  = (const float*)d_in[3];
    const float* w1  = (const float*)d_in[4];
    const float* g1  = (const float*)d_in[5];
    const float* b1  = (const float*)d_in[6];

    int N      = in_sizes[0] / 5;
    int V      = out_size / 132;
    int Npad   = (N + 255) & ~255;
    int ntiles = Npad / 64;
    int nwin2  = (Npad + 127) / 128;

    char* ws = (char*)d_ws;
    size_t off = 0;
    auto alloc = [&](size_t bytes) { size_t r = off; off = (off + bytes + 255) & ~(size_t)255; return r; };

    float4* pts4    = (float4*)(ws + alloc((size_t)Npad * 16));
    int*    vS      = (int*)(ws + alloc((size_t)Npad * 4));
    size_t  zOff    = off;                                   // zero block start
    int*    cnt     = (int*)(ws + alloc((size_t)M_IDS * 4));
    int*    cursor  = (int*)(ws + alloc((size_t)M_IDS * 4));
    float*  stats   = (float*)(ws + alloc(320 * 4));         // bn0: 64 | bn1: 256
    int*    np      = (int*)(ws + alloc(4));
    size_t  zBytes  = off - zOff;
    int*    bOff    = (int*)(ws + alloc((size_t)M_IDS * 4));
    int*    idxArr  = (int*)(ws + alloc((size_t)M_IDS * 4));
    int*    vOff    = (int*)(ws + alloc((size_t)M_IDS * 4));
    int*    vCnt    = (int*)(ws + alloc((size_t)M_IDS * 4));
    int*    totO    = (int*)(ws + alloc(1024 * 4));
    int*    totC    = (int*)(ws + alloc(1024 * 4));
    int*    baseO   = (int*)(ws + alloc(1024 * 4));
    int*    baseC   = (int*)(ws + alloc(1024 * 4));
    float*  sb0     = (float*)(ws + alloc(64 * 4));
    float*  sb1     = (float*)(ws + alloc(256 * 4));
    float*  sPart   = (float*)(ws + alloc((size_t)256 * NBA * 4));
    float4* meanArr = (float4*)(ws + alloc((size_t)V * 16));
    uint16_t* XpL   = (uint16_t*)(ws + alloc((size_t)Npad * 32 * 2));
    uint16_t* xmaxV = (uint16_t*)(ws + alloc((size_t)V * 32 * 2));
    (void)ws_size;

    hipMemsetAsync(ws + zOff, 0, zBytes, stream);
    hipMemsetAsync(vS, 0xFF, (size_t)Npad * 4, stream);

    int blocksN = (N + 255) / 256;
    float* outF = (float*)d_out;

    k1_count<<<blocksN, 256, 0, stream>>>(pts, cnt, N);
    k2a_tot<<<NCHUNK, CH, 0, stream>>>(cnt, totO, totC, np);
    k2b_scan<<<1, 1024, 0, stream>>>(totO, totC, baseO, baseC);
    k2c_index<<<NCHUNK, CH, 0, stream>>>(cnt, baseO, baseC, idxArr, bOff, vOff, vCnt,
                                         outF, V);
    k3_order<<<blocksN, 256, 0, stream>>>(pts, bOff, idxArr, cursor, pts4, vS, N);
    k4_mean<<<(V + 255) / 256, 256, 0, stream>>>(pts4, vOff, vCnt, meanArr, V);
    k5_y0<<<1024, 256, 0, stream>>>(pts4, w0, vS, meanArr, XpL, stats, Npad);
    k_bnfin<<<1, 32, 0, stream>>>(stats, np, g0, b0, sb0, 32);
    k8_xmax<<<(V + 3) / 4, 256, 0, stream>>>(XpL, vOff, vCnt, sb0,
                                             (uint32_t*)xmaxV, V);
    kA_stats<<<NBA, 256, 0, stream>>>(XpL, xmaxV, w1, vS, np, sPart, nwin2);
    k_red1<<<256, 256, 0, stream>>>(sPart, stats + 64);
    k_bnfin<<<1, 128, 0, stream>>>(stats + 64, np, g1, b1, sb1, 128);
    kB_mapply<<<NBB, 256, 0, stream>>>(XpL, xmaxV, w1, vS, vOff, vCnt, np, sb1,
                                       outF, ntiles);
}

// Round 9
// 553.631 us; speedup vs baseline: 1.1361x; 1.0545x over previous
//
#include <hip/hip_runtime.h>
#include <cstdint>
#include <cstddef>

// ConvVFE: voxelize -> per-voxel mean -> MLP(10->32)+BN+ReLU -> voxel max
// -> concat -> MLP(64->128)+BN+ReLU -> voxel max ; plus voxel coords.
//
// R13: R12 (zero-barrier kB) = 584us best, kB 168us. Three falsified
// theories for kB's ~170us floor: VALU-bound (R11), barrier-bound (R12),
// frag-load-latency (R10). Remaining shared term: the gather's serial
// per-voxel metadata chain -- 2 dependent wave-uniform global loads
// (vOff[g], vCnt[g], ~200cyc each) per voxel, ~7 voxels/window.
// This round (single change): voxels in [gFirst,gLast] are CONTIGUOUS and
// nvox<=32, so lane i preloads vOff/vCnt[gFirst+i] in ONE coalesced load
// pair, hoisted BEFORE the MFMA block (latency hides under compute); the
// voxel loop reads them via __shfl. Everything else identical to R12.

constexpr int M_IDS  = 220000;
constexpr int CH     = 256;
constexpr int NCHUNK = (M_IDS + CH - 1) / CH;   // 860
constexpr int NBA    = 1024;                    // kA grid / stats partials
constexpr int NBB    = 2048;                    // kB grid
constexpr int EWS    = 66;                      // wave-private els row stride (f32)

typedef __attribute__((ext_vector_type(8))) __bf16          bf16x8;
typedef __attribute__((ext_vector_type(8))) unsigned short  u16x8;
typedef __attribute__((ext_vector_type(4))) float           f32x4;

union U8 { u16x8 u; bf16x8 b; };

__device__ __forceinline__ uint16_t f2b(float f) {
    uint32_t u = __float_as_uint(f);
    u += 0x7fffu + ((u >> 16) & 1u);
    return (uint16_t)(u >> 16);
}
__device__ __forceinline__ float b2f(uint16_t h) {
    return __uint_as_float(((uint32_t)h) << 16);
}

__device__ __forceinline__ f32x4 mfma16(bf16x8 a, bf16x8 b, f32x4 c) {
    return __builtin_amdgcn_mfma_f32_16x16x32_bf16(a, b, c, 0, 0, 0);
}

// ---------------------------------------------------------------- voxel id (shared by k1/k3)
__device__ __forceinline__ int voxel_id(const float* __restrict__ p) {
    float b = p[0], x = p[1], y = p[2], z = p[3];
    float fx = floorf((x - 0.0f) / 0.32f);
    float fy = floorf((y + 40.0f) / 0.32f);
    float fz = floorf((z + 3.0f) / 4.0f);
    bool ok = (fx >= 0.0f) && (fx < 220.0f) && (fy >= 0.0f) && (fy < 250.0f) &&
              (fz >= 0.0f) && (fz < 1.0f);
    if (!ok) return -1;
    return (int)b * 55000 + (int)fx * 250 + (int)fy + (int)fz;
}

// ---------------------------------------------------------------- k1: histogram only
__global__ void k1_count(const float* __restrict__ pts, int* __restrict__ cnt, int N)
{
    int i = blockIdx.x * blockDim.x + threadIdx.x;
    if (i >= N) return;
    int m = voxel_id(pts + (size_t)i * 5);
    if (m >= 0) atomicAdd(&cnt[m], 1);
}

// ---------------------------------------------------------------- k2: two-level scans
__global__ void k2a_tot(const int* __restrict__ cnt, int* __restrict__ totO,
                        int* __restrict__ totC, int* __restrict__ np)
{
    __shared__ int so[CH], sc[CH];
    int t = threadIdx.x;
    int id = blockIdx.x * CH + t;
    int c = (id < M_IDS) ? cnt[id] : 0;
    so[t] = (c > 0) ? 1 : 0;
    sc[t] = c;
    __syncthreads();
    for (int s = CH / 2; s > 0; s >>= 1) {
        if (t < s) { so[t] += so[t + s]; sc[t] += sc[t + s]; }
        __syncthreads();
    }
    if (t == 0) { totO[blockIdx.x] = so[0]; totC[blockIdx.x] = sc[0]; atomicAdd(np, sc[0]); }
}

__global__ void k2b_scan(const int* __restrict__ totO, const int* __restrict__ totC,
                         int* __restrict__ baseO, int* __restrict__ baseC)
{
    __shared__ int a[1024], bb[1024];
    int t = threadIdx.x;
    int vo = (t < NCHUNK) ? totO[t] : 0;
    int vc = (t < NCHUNK) ? totC[t] : 0;
    a[t] = vo; bb[t] = vc;
    __syncthreads();
    for (int off = 1; off < 1024; off <<= 1) {
        int xa = (t >= off) ? a[t - off] : 0;
        int xb = (t >= off) ? bb[t - off] : 0;
        __syncthreads();
        a[t] += xa; bb[t] += xb;
        __syncthreads();
    }
    baseO[t] = a[t] - vo;   // exclusive
    baseC[t] = bb[t] - vc;
}

__global__ void k2c_index(const int* __restrict__ cnt, const int* __restrict__ baseO,
                          const int* __restrict__ baseC, int* __restrict__ idxArr,
                          int* __restrict__ bOff, int* __restrict__ vOff,
                          int* __restrict__ vCnt, float* __restrict__ outF, int V)
{
    __shared__ int a[CH], bb[CH];
    int t = threadIdx.x;
    int id = blockIdx.x * CH + t;
    int c = (id < M_IDS) ? cnt[id] : 0;
    int occ = (c > 0) ? 1 : 0;
    a[t] = occ; bb[t] = c;
    __syncthreads();
    for (int off = 1; off < CH; off <<= 1) {
        int xa = (t >= off) ? a[t - off] : 0;
        int xb = (t >= off) ? bb[t - off] : 0;
        __syncthreads();
        a[t] += xa; bb[t] += xb;
        __syncthreads();
    }
    if (id >= M_IDS) return;
    int g  = baseO[blockIdx.x] + a[t] - occ;
    int bo = baseC[blockIdx.x] + bb[t] - c;
    idxArr[id] = g;
    bOff[id]   = bo;
    if (occ) {
        vOff[g] = bo;
        vCnt[g] = c;
        float* outCoords = outF + (size_t)V * 128;
        int b2 = id / 55000;
        int rm = id % 55000;
        int cx = rm / 250;
        int cy = rm % 250;
        outCoords[(size_t)g * 4 + 0] = (float)b2;
        outCoords[(size_t)g * 4 + 1] = 0.0f;
        outCoords[(size_t)g * 4 + 2] = (float)cy;
        outCoords[(size_t)g * 4 + 3] = (float)cx;
        // zero-init ONLY voxels straddling a 32-row window (interior ones get
        // a plain store from their owning wave in kB; out memset deleted)
        if ((bo >> 5) != ((bo + c - 1) >> 5)) {
            float4* of = (float4*)(outF + (size_t)g * 128);
            float4 z = make_float4(0.f, 0.f, 0.f, 0.f);
#pragma unroll
            for (int k = 0; k < 32; k++) of[k] = z;
        }
    }
}

// ---------------------------------------------------------------- k3: scatter point payload to sorted order
__global__ void k3_order(const float* __restrict__ pts, const int* __restrict__ bOff,
                         const int* __restrict__ idxArr, int* __restrict__ cursor,
                         float4* __restrict__ pts4, int* __restrict__ vS, int N)
{
    int i = blockIdx.x * blockDim.x + threadIdx.x;
    if (i >= N) return;
    const float* p = pts + (size_t)i * 5;
    int m = voxel_id(p);
    if (m < 0) return;
    int slot = atomicAdd(&cursor[m], 1);
    int j = bOff[m] + slot;
    pts4[j] = make_float4(p[1], p[2], p[3], p[4]);
    vS[j]   = idxArr[m];
}

// ---------------------------------------------------------------- k4: per-voxel xyz mean (contiguous)
__global__ void k4_mean(const float4* __restrict__ pts4, const int* __restrict__ vOff,
                        const int* __restrict__ vCnt, float4* __restrict__ meanArr, int V)
{
    int g = blockIdx.x * blockDim.x + threadIdx.x;
    if (g >= V) return;
    int off = vOff[g], c = vCnt[g];
    float sx = 0.0f, sy = 0.0f, sz = 0.0f;
    for (int p = 0; p < c; p++) {
        float4 q = pts4[off + p];
        sx += q.x; sy += q.y; sz += q.z;
    }
    float ic = 1.0f / (float)c;
    meanArr[g] = make_float4(sx * ic, sy * ic, sz * ic, 0.0f);
}

// ---------------------------------------------------------------- k5: y0 = feats @ w0 (raw bf16, contiguous) + BN0 stats
__global__ __launch_bounds__(256)
void k5_y0(const float4* __restrict__ pts4, const float* __restrict__ w0,
           const int* __restrict__ vS, const float4* __restrict__ meanArr,
           uint16_t* __restrict__ XpL, float* __restrict__ stats0, int Npad)
{
    __shared__ float sl[64];
    int t = threadIdx.x;
    if (t < 64) sl[t] = 0.0f;
    __syncthreads();
    float s[32], q[32];
#pragma unroll
    for (int c = 0; c < 32; c++) { s[c] = 0.0f; q[c] = 0.0f; }

    for (int j = blockIdx.x * 256 + t; j < Npad; j += gridDim.x * 256) {
        int v = vS[j];
        if (v < 0) continue;             // pad/invalid rows: never read (vS guard)
        float4 P = pts4[j];
        float4 mn = meanArr[v];
        float x = P.x, y = P.y, z = P.z, it = P.w;
        float fx = floorf(x / 0.32f);
        float fy = floorf((y + 40.0f) / 0.32f);
        float f[10];
        f[0] = x; f[1] = y; f[2] = z; f[3] = it;
        f[4] = x - mn.x; f[5] = y - mn.y; f[6] = z - mn.z;
        f[7] = x - (fx * 0.32f + 0.16f);
        f[8] = y - (fy * 0.32f - 39.84f);
        f[9] = z + 1.0f;
        float y0[32];
#pragma unroll
        for (int c = 0; c < 32; c++) y0[c] = 0.0f;
#pragma unroll
        for (int d = 0; d < 10; d++) {
            float fd = f[d];
#pragma unroll
            for (int c = 0; c < 32; c++) y0[c] += fd * w0[d * 32 + c];
        }
        uint32_t pk[16];
#pragma unroll
        for (int k = 0; k < 16; k++)
            pk[k] = (uint32_t)f2b(y0[2 * k]) | ((uint32_t)f2b(y0[2 * k + 1]) << 16);
        uint4* rp = (uint4*)(XpL + (size_t)j * 32);
        rp[0] = make_uint4(pk[0], pk[1], pk[2], pk[3]);
        rp[1] = make_uint4(pk[4], pk[5], pk[6], pk[7]);
        rp[2] = make_uint4(pk[8], pk[9], pk[10], pk[11]);
        rp[3] = make_uint4(pk[12], pk[13], pk[14], pk[15]);
#pragma unroll
        for (int c = 0; c < 32; c++) { s[c] += y0[c]; q[c] += y0[c] * y0[c]; }
    }

    int lane = t & 63;
#pragma unroll
    for (int c = 0; c < 32; c++) {
#pragma unroll
        for (int m2 = 1; m2 < 64; m2 <<= 1) {
            s[c] += __shfl_xor(s[c], m2);
            q[c] += __shfl_xor(q[c], m2);
        }
        if (lane == c) { atomicAdd(&sl[c], s[c]); atomicAdd(&sl[32 + c], q[c]); }
    }
    __syncthreads();
    if (t < 64) atomicAdd(&stats0[t], sl[t]);
}

// ---------------------------------------------------------------- BN finalize
__global__ void k_bnfin(const float* __restrict__ stats, const int* __restrict__ np,
                        const float* __restrict__ g, const float* __restrict__ b,
                        float* __restrict__ sb, int C)
{
    int c = blockIdx.x * blockDim.x + threadIdx.x;
    if (c >= C) return;
    float n   = (float)(*np);
    float mu  = stats[c] / n;
    float var = stats[C + c] / n - mu * mu;
    float s   = g[c] / sqrtf(var + 1e-3f);
    sb[c]     = s;
    sb[C + c] = b[c] - mu * s;
}

// ---------------------------------------------------------------- k8: BN0 apply (writeback) + voxel max -> xmaxV
__global__ __launch_bounds__(256)
void k8_xmax(uint16_t* __restrict__ XpL, const int* __restrict__ vOff,
             const int* __restrict__ vCnt, const float* __restrict__ sb0,
             uint32_t* __restrict__ xmaxV, int V)
{
    int t = threadIdx.x;
    int g = blockIdx.x * 4 + (t >> 6);
    if (g >= V) return;
    int lane = t & 63;
    int c2 = lane & 15, h = lane >> 4;   // c2: u32 pair of channels, h: row phase
    int ch0 = c2 * 2;
    float sA = sb0[ch0],     bA = sb0[32 + ch0];
    float sB = sb0[ch0 + 1], bB = sb0[33 + ch0];
    int off = vOff[g], n = vCnt[g];
    float m0 = 0.0f, m1 = 0.0f;          // relu >= 0
    for (int i = h; i < n; i += 4) {
        uint32_t* ap = (uint32_t*)(XpL + (size_t)(off + i) * 32 + ch0);
        uint32_t u = *ap;
        float e0 = fmaxf(b2f((uint16_t)u) * sA + bA, 0.0f);
        float e1 = fmaxf(b2f((uint16_t)(u >> 16)) * sB + bB, 0.0f);
        *ap = (uint32_t)f2b(e0) | ((uint32_t)f2b(e1) << 16);
        m0 = fmaxf(m0, e0);
        m1 = fmaxf(m1, e1);
    }
    m0 = fmaxf(m0, __shfl_xor(m0, 16)); m0 = fmaxf(m0, __shfl_xor(m0, 32));
    m1 = fmaxf(m1, __shfl_xor(m1, 16)); m1 = fmaxf(m1, __shfl_xor(m1, 32));
    if (h == 0)
        xmaxV[(size_t)g * 16 + c2] = (uint32_t)f2b(m0) | ((uint32_t)f2b(m1) << 16);
}

// ---------------------------------------------------------------- W frags: bf16 hi/lo split of w1
__device__ __forceinline__ void load_wsplit(const float* __restrict__ w1, int cb,
                                            int l15, int lg, bf16x8* Bhi, bf16x8* Blo)
{
    int col = cb + l15;
    int kr  = lg * 8;
#pragma unroll
    for (int nb = 0; nb < 4; nb++) {
#pragma unroll
        for (int ks = 0; ks < 2; ks++) {
            U8 h, l;
#pragma unroll
            for (int jj = 0; jj < 8; jj++) {
                float w = w1[(ks * 32 + kr + jj) * 128 + col + nb * 16];
                uint16_t hb = f2b(w);
                h.u[jj] = hb;
                l.u[jj] = f2b(w - b2f(hb));
            }
            Bhi[nb * 2 + ks] = h.b;
            Blo[nb * 2 + ks] = l.b;
        }
    }
}

// ---------------------------------------------------------------- frag fetch (lower from XpL, upper from xmaxV via vS)
__device__ __forceinline__ void load_afrags(const uint16_t* __restrict__ XpL,
                                            const uint16_t* __restrict__ xmaxV,
                                            const int* __restrict__ vS,
                                            int tb, int rowSel, int l15, int lg,
                                            U8* aL, U8* aU)
{
#pragma unroll
    for (int m = 0; m < 2; m++) {
        int r = tb + rowSel * 32 + m * 16 + l15;
        int v = vS[r];                   // pad rows: -1 (memset)
        if (v >= 0) {
            aL[m].u = *(const u16x8*)(XpL + (size_t)r * 32 + lg * 8);
            aU[m].u = *(const u16x8*)(xmaxV + (size_t)v * 32 + lg * 8);
        } else {
#pragma unroll
            for (int j = 0; j < 8; j++) { aL[m].u[j] = 0; aU[m].u[j] = 0; }
        }
    }
}

// ---------------------------------------------------------------- kA: streaming stats GEMM (no barriers in loop)
__global__ __launch_bounds__(256)
void kA_stats(const uint16_t* __restrict__ XpL, const uint16_t* __restrict__ xmaxV,
              const float* __restrict__ w1, const int* __restrict__ vS,
              const int* __restrict__ np, float* __restrict__ sPart, int nwin2)
{
    __shared__ float fl[512];
    int t = threadIdx.x;
    int wv = t >> 6, lane = t & 63;
    int l15 = lane & 15, lg = lane >> 4;
    int rowSel = wv & 1, cb = (wv >> 1) * 64;

    bf16x8 Bhi[8], Blo[8];
    load_wsplit(w1, cb, l15, lg, Bhi, Blo);

    int nv = *np;
    float s[4] = {0.f, 0.f, 0.f, 0.f}, q[4] = {0.f, 0.f, 0.f, 0.f};

    for (int win = blockIdx.x; win < nwin2; win += gridDim.x) {
        int wb = win * 128;
        if (wb >= nv) break;
#pragma unroll
        for (int sub = 0; sub < 2; sub++) {
            int tb = wb + sub * 64;
            U8 aL[2], aU[2];
            load_afrags(XpL, xmaxV, vS, tb, rowSel, l15, lg, aL, aU);
            f32x4 acc[2][4];
#pragma unroll
            for (int m = 0; m < 2; m++)
#pragma unroll
                for (int nb = 0; nb < 4; nb++)
                    acc[m][nb] = (f32x4){0.f, 0.f, 0.f, 0.f};
#pragma unroll
            for (int m = 0; m < 2; m++)
#pragma unroll
                for (int nb = 0; nb < 4; nb++) {
                    acc[m][nb] = mfma16(aL[m].b, Bhi[nb * 2],     acc[m][nb]);
                    acc[m][nb] = mfma16(aL[m].b, Blo[nb * 2],     acc[m][nb]);
                    acc[m][nb] = mfma16(aU[m].b, Bhi[nb * 2 + 1], acc[m][nb]);
                    acc[m][nb] = mfma16(aU[m].b, Blo[nb * 2 + 1], acc[m][nb]);
                }
#pragma unroll
            for (int m = 0; m < 2; m++)
#pragma unroll
                for (int nb = 0; nb < 4; nb++)
#pragma unroll
                    for (int r = 0; r < 4; r++) {
                        float y = acc[m][nb][r];
                        s[nb] += y; q[nb] += y * y;
                    }
        }
    }
#pragma unroll
    for (int nb = 0; nb < 4; nb++) {
        s[nb] += __shfl_xor(s[nb], 16); s[nb] += __shfl_xor(s[nb], 32);
        q[nb] += __shfl_xor(q[nb], 16); q[nb] += __shfl_xor(q[nb], 32);
    }
    if (lane < 16) {
#pragma unroll
        for (int nb = 0; nb < 4; nb++) {
            int ch = cb + nb * 16 + lane;
            fl[rowSel * 128 + ch]       = s[nb];
            fl[256 + rowSel * 128 + ch] = q[nb];
        }
    }
    __syncthreads();
    if (t < 128)
        sPart[(size_t)t * NBA + blockIdx.x] = fl[t] + fl[128 + t];
    else {
        int ch = t - 128;
        sPart[(size_t)(128 + ch) * NBA + blockIdx.x] = fl[256 + ch] + fl[384 + ch];
    }
}

// ---------------------------------------------------------------- reduce stat partials
__global__ void k_red1(const float* __restrict__ part, float* __restrict__ stats1)
{
    __shared__ float red[4];
    int o = blockIdx.x, t = threadIdx.x;
    float s = 0.0f;
    for (int k = t; k < NBA; k += 256) s += part[(size_t)o * NBA + k];
#pragma unroll
    for (int m = 1; m < 64; m <<= 1) s += __shfl_xor(s, m);
    if ((t & 63) == 0) red[t >> 6] = s;
    __syncthreads();
    if (t == 0) stats1[o] = red[0] + red[1] + red[2] + red[3];
}

// ---------------------------------------------------------------- kB: MFMA GEMM + BN1 + ReLU + voxel gather-max
//      zero barriers; gather metadata preloaded in parallel (1 coalesced
//      load pair per window, shuffled to the serial voxel loop)
__global__ __launch_bounds__(256)
void kB_mapply(const uint16_t* __restrict__ XpL, const uint16_t* __restrict__ xmaxV,
               const float* __restrict__ w1, const int* __restrict__ vS,
               const int* __restrict__ vOff, const int* __restrict__ vCnt,
               const int* __restrict__ np, const float* __restrict__ sb1,
               float* __restrict__ outF, int ntiles)
{
    __shared__ float els[4][32 * EWS];   // wave-private f32 stage (33.8KB)
    int t = threadIdx.x;
    int wv = t >> 6, lane = t & 63;
    int l15 = lane & 15, lg = lane >> 4;
    int rowSel = wv & 1, cb = (wv >> 1) * 64;
    float* ew = els[wv];

    bf16x8 Bhi[8], Blo[8];
    load_wsplit(w1, cb, l15, lg, Bhi, Blo);

    float sc[4], bc[4];
#pragma unroll
    for (int nb = 0; nb < 4; nb++) {
        int c = cb + nb * 16 + l15;
        sc[nb] = sb1[c];
        bc[nb] = sb1[128 + c];
    }

    int nv = *np;

    for (int tile = blockIdx.x; tile < ntiles; tile += gridDim.x) {
        int tb = tile * 64;
        if (tb >= nv) break;             // uniform across block
        int tw = tb + rowSel * 32;       // this wave's 32-row window
        if (tw >= nv) continue;          // wave-uniform: window fully padded
        U8 aL[2], aU[2];
        load_afrags(XpL, xmaxV, vS, tb, rowSel, l15, lg, aL, aU);
        // gather metadata: issued here so latency hides under the MFMAs.
        // voxels [gFirst,gLast] are contiguous, nvox <= 32 (each owns >=1 of
        // the window's rows) -> lane i preloads vOff/vCnt[gFirst+i].
        int lastRow = nv - 1 - tw; if (lastRow > 31) lastRow = 31;
        int gFirst = vS[tw];
        int gLast  = vS[tw + lastRow];
        int nvox   = gLast - gFirst + 1;
        int myOff = 0, myCnt = 0;
        if (lane < nvox) {
            myOff = vOff[gFirst + lane];
            myCnt = vCnt[gFirst + lane];
        }
        f32x4 acc[2][4];
#pragma unroll
        for (int m = 0; m < 2; m++)
#pragma unroll
            for (int nb = 0; nb < 4; nb++)
                acc[m][nb] = (f32x4){0.f, 0.f, 0.f, 0.f};
#pragma unroll
        for (int m = 0; m < 2; m++)
#pragma unroll
            for (int nb = 0; nb < 4; nb++) {
                acc[m][nb] = mfma16(aL[m].b, Bhi[nb * 2],     acc[m][nb]);
                acc[m][nb] = mfma16(aL[m].b, Blo[nb * 2],     acc[m][nb]);
                acc[m][nb] = mfma16(aU[m].b, Bhi[nb * 2 + 1], acc[m][nb]);
                acc[m][nb] = mfma16(aU[m].b, Blo[nb * 2 + 1], acc[m][nb]);
            }
        // stage BN1+ReLU result to the wave's PRIVATE slice (no barrier;
        // ds_write->ds_read ordering is wave-local, compiler inserts waits)
#pragma unroll
        for (int m = 0; m < 2; m++) {
            int rloc = m * 16 + lg * 4;  // 0..31 within the window
#pragma unroll
            for (int nb = 0; nb < 4; nb++) {
                int ci = nb * 16 + l15;  // 0..63 within the wave's channels
#pragma unroll
                for (int r = 0; r < 4; r++)
                    ew[(rloc + r) * EWS + ci] =
                        fmaxf(acc[m][nb][r] * sc[nb] + bc[nb], 0.0f);
            }
        }
        // gather: lane l owns channel cb+l over this wave's 32-row window;
        // per-voxel metadata comes from the preloaded lanes via shuffle
        for (int g = gFirst; g <= gLast; g++) {
            int idx  = g - gFirst;       // wave-uniform
            int offv = __shfl(myOff, idx);
            int cntv = __shfl(myCnt, idx);
            int endv = offv + cntv;
            int a  = offv > tw ? offv : tw;
            int e2 = endv < tw + 32 ? endv : tw + 32;
            float mx = 0.0f;
            for (int p = a; p < e2; p++)
                mx = fmaxf(mx, ew[(p - tw) * EWS + lane]);
            size_t oa = (size_t)g * 128 + cb + lane;
            if (offv >= tw && endv <= tw + 32) outF[oa] = mx;            // window-interior
            else if (mx > 0.0f)
                atomicMax((unsigned int*)&outF[oa], __float_as_uint(mx)); // straddler
        }
    }
}

// ---------------------------------------------------------------- launch
extern "C" void kernel_launch(void* const* d_in, const int* in_sizes, int n_in,
                              void* d_out, int out_size, void* d_ws, size_t ws_size,
                              hipStream_t stream)
{
    const float* pts = (const float*)d_in[0];
    const float* w0  = (const float*)d_in[1];
    const float* g0  = (const float*)d_in[2];
    const float* b0  = (const float*)d_in[3];
    const float* w1  = (const float*)d_in[4];
    const float* g1  = (const float*)d_in[5];
    const float* b1  = (const float*)d_in[6];

    int N      = in_sizes[0] / 5;
    int V      = out_size / 132;
    int Npad   = (N + 255) & ~255;
    int ntiles = Npad / 64;
    int nwin2  = (Npad + 127) / 128;

    char* ws = (char*)d_ws;
    size_t off = 0;
    auto alloc = [&](size_t bytes) { size_t r = off; off = (off + bytes + 255) & ~(size_t)255; return r; };

    float4* pts4    = (float4*)(ws + alloc((size_t)Npad * 16));
    int*    vS      = (int*)(ws + alloc((size_t)Npad * 4));
    size_t  zOff    = off;                                   // zero block start
    int*    cnt     = (int*)(ws + alloc((size_t)M_IDS * 4));
    int*    cursor  = (int*)(ws + alloc((size_t)M_IDS * 4));
    float*  stats   = (float*)(ws + alloc(320 * 4));         // bn0: 64 | bn1: 256
    int*    np      = (int*)(ws + alloc(4));
    size_t  zBytes  = off - zOff;
    int*    bOff    = (int*)(ws + alloc((size_t)M_IDS * 4));
    int*    idxArr  = (int*)(ws + alloc((size_t)M_IDS * 4));
    int*    vOff    = (int*)(ws + alloc((size_t)M_IDS * 4));
    int*    vCnt    = (int*)(ws + alloc((size_t)M_IDS * 4));
    int*    totO    = (int*)(ws + alloc(1024 * 4));
    int*    totC    = (int*)(ws + alloc(1024 * 4));
    int*    baseO   = (int*)(ws + alloc(1024 * 4));
    int*    baseC   = (int*)(ws + alloc(1024 * 4));
    float*  sb0     = (float*)(ws + alloc(64 * 4));
    float*  sb1     = (float*)(ws + alloc(256 * 4));
    float*  sPart   = (float*)(ws + alloc((size_t)256 * NBA * 4));
    float4* meanArr = (float4*)(ws + alloc((size_t)V * 16));
    uint16_t* XpL   = (uint16_t*)(ws + alloc((size_t)Npad * 32 * 2));
    uint16_t* xmaxV = (uint16_t*)(ws + alloc((size_t)V * 32 * 2));
    (void)ws_size;

    hipMemsetAsync(ws + zOff, 0, zBytes, stream);
    hipMemsetAsync(vS, 0xFF, (size_t)Npad * 4, stream);

    int blocksN = (N + 255) / 256;
    float* outF = (float*)d_out;

    k1_count<<<blocksN, 256, 0, stream>>>(pts, cnt, N);
    k2a_tot<<<NCHUNK, CH, 0, stream>>>(cnt, totO, totC, np);
    k2b_scan<<<1, 1024, 0, stream>>>(totO, totC, baseO, baseC);
    k2c_index<<<NCHUNK, CH, 0, stream>>>(cnt, baseO, baseC, idxArr, bOff, vOff, vCnt,
                                         outF, V);
    k3_order<<<blocksN, 256, 0, stream>>>(pts, bOff, idxArr, cursor, pts4, vS, N);
    k4_mean<<<(V + 255) / 256, 256, 0, stream>>>(pts4, vOff, vCnt, meanArr, V);
    k5_y0<<<1024, 256, 0, stream>>>(pts4, w0, vS, meanArr, XpL, stats, Npad);
    k_bnfin<<<1, 32, 0, stream>>>(stats, np, g0, b0, sb0, 32);
    k8_xmax<<<(V + 3) / 4, 256, 0, stream>>>(XpL, vOff, vCnt, sb0,
                                             (uint32_t*)xmaxV, V);
    kA_stats<<<NBA, 256, 0, stream>>>(XpL, xmaxV, w1, vS, np, sPart, nwin2);
    k_red1<<<256, 256, 0, stream>>>(sPart, stats + 64);
    k_bnfin<<<1, 128, 0, stream>>>(stats + 64, np, g1, b1, sb1, 128);
    kB_mapply<<<NBB, 256, 0, stream>>>(XpL, xmaxV, w1, vS, vOff, vCnt, np, sb1,
                                       outF, ntiles);
}

// Round 10
// 539.687 us; speedup vs baseline: 1.1655x; 1.0258x over previous
//
#include <hip/hip_runtime.h>
#include <cstdint>
#include <cstddef>

// ConvVFE: voxelize -> per-voxel mean -> MLP(10->32)+BN+ReLU -> voxel max
// -> concat -> MLP(64->128)+BN+ReLU -> voxel max ; plus voxel coords.
//
// R14: R13 metadata-preload hit its prediction (kB 168->142us, VALU 63%,
// Mfma 9.2% -> issue-bound now, 72% slots busy). Slot census: gather ~230
// + staging ~110 of ~460/tile. This round cuts LDS instruction count 4x:
//  - els -> per-wave CHANNEL-MAJOR [64ch][36dw] with slot rotation
//    slot=(rowGroup + ch>>3)&7: both the 8 ds_write_b128 (stage) and the
//    8 ds_read_b128 (gather) spread exactly 8 lanes/bank-group (b128
//    optimum; residue-counted). 16B alignment: ch*144 + slot*16.
//  - gather: linear scan over 32 rows in b128 groups; voxel flush driven
//    by register metadata (R13 preload) via readfirstlane'd scalar cmps.
//    Per row ~1 VALU fmax instead of ~5.
// Everything outside kB identical to R13 (best: 554us; kB 142us).

constexpr int M_IDS  = 220000;
constexpr int CH     = 256;
constexpr int NCHUNK = (M_IDS + CH - 1) / CH;   // 860
constexpr int NBA    = 1024;                    // kA grid / stats partials
constexpr int NBB    = 2048;                    // kB grid
constexpr int CSTR   = 36;                      // els channel stride (dwords)

typedef __attribute__((ext_vector_type(8))) __bf16          bf16x8;
typedef __attribute__((ext_vector_type(8))) unsigned short  u16x8;
typedef __attribute__((ext_vector_type(4))) float           f32x4;

union U8 { u16x8 u; bf16x8 b; };

__device__ __forceinline__ uint16_t f2b(float f) {
    uint32_t u = __float_as_uint(f);
    u += 0x7fffu + ((u >> 16) & 1u);
    return (uint16_t)(u >> 16);
}
__device__ __forceinline__ float b2f(uint16_t h) {
    return __uint_as_float(((uint32_t)h) << 16);
}

__device__ __forceinline__ f32x4 mfma16(bf16x8 a, bf16x8 b, f32x4 c) {
    return __builtin_amdgcn_mfma_f32_16x16x32_bf16(a, b, c, 0, 0, 0);
}

// ---------------------------------------------------------------- voxel id (shared by k1/k3)
__device__ __forceinline__ int voxel_id(const float* __restrict__ p) {
    float b = p[0], x = p[1], y = p[2], z = p[3];
    float fx = floorf((x - 0.0f) / 0.32f);
    float fy = floorf((y + 40.0f) / 0.32f);
    float fz = floorf((z + 3.0f) / 4.0f);
    bool ok = (fx >= 0.0f) && (fx < 220.0f) && (fy >= 0.0f) && (fy < 250.0f) &&
              (fz >= 0.0f) && (fz < 1.0f);
    if (!ok) return -1;
    return (int)b * 55000 + (int)fx * 250 + (int)fy + (int)fz;
}

// ---------------------------------------------------------------- k1: histogram only
__global__ void k1_count(const float* __restrict__ pts, int* __restrict__ cnt, int N)
{
    int i = blockIdx.x * blockDim.x + threadIdx.x;
    if (i >= N) return;
    int m = voxel_id(pts + (size_t)i * 5);
    if (m >= 0) atomicAdd(&cnt[m], 1);
}

// ---------------------------------------------------------------- k2: two-level scans
__global__ void k2a_tot(const int* __restrict__ cnt, int* __restrict__ totO,
                        int* __restrict__ totC, int* __restrict__ np)
{
    __shared__ int so[CH], sc[CH];
    int t = threadIdx.x;
    int id = blockIdx.x * CH + t;
    int c = (id < M_IDS) ? cnt[id] : 0;
    so[t] = (c > 0) ? 1 : 0;
    sc[t] = c;
    __syncthreads();
    for (int s = CH / 2; s > 0; s >>= 1) {
        if (t < s) { so[t] += so[t + s]; sc[t] += sc[t + s]; }
        __syncthreads();
    }
    if (t == 0) { totO[blockIdx.x] = so[0]; totC[blockIdx.x] = sc[0]; atomicAdd(np, sc[0]); }
}

__global__ void k2b_scan(const int* __restrict__ totO, const int* __restrict__ totC,
                         int* __restrict__ baseO, int* __restrict__ baseC)
{
    __shared__ int a[1024], bb[1024];
    int t = threadIdx.x;
    int vo = (t < NCHUNK) ? totO[t] : 0;
    int vc = (t < NCHUNK) ? totC[t] : 0;
    a[t] = vo; bb[t] = vc;
    __syncthreads();
    for (int off = 1; off < 1024; off <<= 1) {
        int xa = (t >= off) ? a[t - off] : 0;
        int xb = (t >= off) ? bb[t - off] : 0;
        __syncthreads();
        a[t] += xa; bb[t] += xb;
        __syncthreads();
    }
    baseO[t] = a[t] - vo;   // exclusive
    baseC[t] = bb[t] - vc;
}

__global__ void k2c_index(const int* __restrict__ cnt, const int* __restrict__ baseO,
                          const int* __restrict__ baseC, int* __restrict__ idxArr,
                          int* __restrict__ bOff, int* __restrict__ vOff,
                          int* __restrict__ vCnt, float* __restrict__ outF, int V)
{
    __shared__ int a[CH], bb[CH];
    int t = threadIdx.x;
    int id = blockIdx.x * CH + t;
    int c = (id < M_IDS) ? cnt[id] : 0;
    int occ = (c > 0) ? 1 : 0;
    a[t] = occ; bb[t] = c;
    __syncthreads();
    for (int off = 1; off < CH; off <<= 1) {
        int xa = (t >= off) ? a[t - off] : 0;
        int xb = (t >= off) ? bb[t - off] : 0;
        __syncthreads();
        a[t] += xa; bb[t] += xb;
        __syncthreads();
    }
    if (id >= M_IDS) return;
    int g  = baseO[blockIdx.x] + a[t] - occ;
    int bo = baseC[blockIdx.x] + bb[t] - c;
    idxArr[id] = g;
    bOff[id]   = bo;
    if (occ) {
        vOff[g] = bo;
        vCnt[g] = c;
        float* outCoords = outF + (size_t)V * 128;
        int b2 = id / 55000;
        int rm = id % 55000;
        int cx = rm / 250;
        int cy = rm % 250;
        outCoords[(size_t)g * 4 + 0] = (float)b2;
        outCoords[(size_t)g * 4 + 1] = 0.0f;
        outCoords[(size_t)g * 4 + 2] = (float)cy;
        outCoords[(size_t)g * 4 + 3] = (float)cx;
        // zero-init ONLY voxels straddling a 32-row window (interior ones get
        // a plain store from their owning wave in kB; out memset deleted)
        if ((bo >> 5) != ((bo + c - 1) >> 5)) {
            float4* of = (float4*)(outF + (size_t)g * 128);
            float4 z = make_float4(0.f, 0.f, 0.f, 0.f);
#pragma unroll
            for (int k = 0; k < 32; k++) of[k] = z;
        }
    }
}

// ---------------------------------------------------------------- k3: scatter point payload to sorted order
__global__ void k3_order(const float* __restrict__ pts, const int* __restrict__ bOff,
                         const int* __restrict__ idxArr, int* __restrict__ cursor,
                         float4* __restrict__ pts4, int* __restrict__ vS, int N)
{
    int i = blockIdx.x * blockDim.x + threadIdx.x;
    if (i >= N) return;
    const float* p = pts + (size_t)i * 5;
    int m = voxel_id(p);
    if (m < 0) return;
    int slot = atomicAdd(&cursor[m], 1);
    int j = bOff[m] + slot;
    pts4[j] = make_float4(p[1], p[2], p[3], p[4]);
    vS[j]   = idxArr[m];
}

// ---------------------------------------------------------------- k4: per-voxel xyz mean (contiguous)
__global__ void k4_mean(const float4* __restrict__ pts4, const int* __restrict__ vOff,
                        const int* __restrict__ vCnt, float4* __restrict__ meanArr, int V)
{
    int g = blockIdx.x * blockDim.x + threadIdx.x;
    if (g >= V) return;
    int off = vOff[g], c = vCnt[g];
    float sx = 0.0f, sy = 0.0f, sz = 0.0f;
    for (int p = 0; p < c; p++) {
        float4 q = pts4[off + p];
        sx += q.x; sy += q.y; sz += q.z;
    }
    float ic = 1.0f / (float)c;
    meanArr[g] = make_float4(sx * ic, sy * ic, sz * ic, 0.0f);
}

// ---------------------------------------------------------------- k5: y0 = feats @ w0 (raw bf16, contiguous) + BN0 stats
__global__ __launch_bounds__(256)
void k5_y0(const float4* __restrict__ pts4, const float* __restrict__ w0,
           const int* __restrict__ vS, const float4* __restrict__ meanArr,
           uint16_t* __restrict__ XpL, float* __restrict__ stats0, int Npad)
{
    __shared__ float sl[64];
    int t = threadIdx.x;
    if (t < 64) sl[t] = 0.0f;
    __syncthreads();
    float s[32], q[32];
#pragma unroll
    for (int c = 0; c < 32; c++) { s[c] = 0.0f; q[c] = 0.0f; }

    for (int j = blockIdx.x * 256 + t; j < Npad; j += gridDim.x * 256) {
        int v = vS[j];
        if (v < 0) continue;             // pad/invalid rows: never read (vS guard)
        float4 P = pts4[j];
        float4 mn = meanArr[v];
        float x = P.x, y = P.y, z = P.z, it = P.w;
        float fx = floorf(x / 0.32f);
        float fy = floorf((y + 40.0f) / 0.32f);
        float f[10];
        f[0] = x; f[1] = y; f[2] = z; f[3] = it;
        f[4] = x - mn.x; f[5] = y - mn.y; f[6] = z - mn.z;
        f[7] = x - (fx * 0.32f + 0.16f);
        f[8] = y - (fy * 0.32f - 39.84f);
        f[9] = z + 1.0f;
        float y0[32];
#pragma unroll
        for (int c = 0; c < 32; c++) y0[c] = 0.0f;
#pragma unroll
        for (int d = 0; d < 10; d++) {
            float fd = f[d];
#pragma unroll
            for (int c = 0; c < 32; c++) y0[c] += fd * w0[d * 32 + c];
        }
        uint32_t pk[16];
#pragma unroll
        for (int k = 0; k < 16; k++)
            pk[k] = (uint32_t)f2b(y0[2 * k]) | ((uint32_t)f2b(y0[2 * k + 1]) << 16);
        uint4* rp = (uint4*)(XpL + (size_t)j * 32);
        rp[0] = make_uint4(pk[0], pk[1], pk[2], pk[3]);
        rp[1] = make_uint4(pk[4], pk[5], pk[6], pk[7]);
        rp[2] = make_uint4(pk[8], pk[9], pk[10], pk[11]);
        rp[3] = make_uint4(pk[12], pk[13], pk[14], pk[15]);
#pragma unroll
        for (int c = 0; c < 32; c++) { s[c] += y0[c]; q[c] += y0[c] * y0[c]; }
    }

    int lane = t & 63;
#pragma unroll
    for (int c = 0; c < 32; c++) {
#pragma unroll
        for (int m2 = 1; m2 < 64; m2 <<= 1) {
            s[c] += __shfl_xor(s[c], m2);
            q[c] += __shfl_xor(q[c], m2);
        }
        if (lane == c) { atomicAdd(&sl[c], s[c]); atomicAdd(&sl[32 + c], q[c]); }
    }
    __syncthreads();
    if (t < 64) atomicAdd(&stats0[t], sl[t]);
}

// ---------------------------------------------------------------- BN finalize
__global__ void k_bnfin(const float* __restrict__ stats, const int* __restrict__ np,
                        const float* __restrict__ g, const float* __restrict__ b,
                        float* __restrict__ sb, int C)
{
    int c = blockIdx.x * blockDim.x + threadIdx.x;
    if (c >= C) return;
    float n   = (float)(*np);
    float mu  = stats[c] / n;
    float var = stats[C + c] / n - mu * mu;
    float s   = g[c] / sqrtf(var + 1e-3f);
    sb[c]     = s;
    sb[C + c] = b[c] - mu * s;
}

// ---------------------------------------------------------------- k8: BN0 apply (writeback) + voxel max -> xmaxV
__global__ __launch_bounds__(256)
void k8_xmax(uint16_t* __restrict__ XpL, const int* __restrict__ vOff,
             const int* __restrict__ vCnt, const float* __restrict__ sb0,
             uint32_t* __restrict__ xmaxV, int V)
{
    int t = threadIdx.x;
    int g = blockIdx.x * 4 + (t >> 6);
    if (g >= V) return;
    int lane = t & 63;
    int c2 = lane & 15, h = lane >> 4;   // c2: u32 pair of channels, h: row phase
    int ch0 = c2 * 2;
    float sA = sb0[ch0],     bA = sb0[32 + ch0];
    float sB = sb0[ch0 + 1], bB = sb0[33 + ch0];
    int off = vOff[g], n = vCnt[g];
    float m0 = 0.0f, m1 = 0.0f;          // relu >= 0
    for (int i = h; i < n; i += 4) {
        uint32_t* ap = (uint32_t*)(XpL + (size_t)(off + i) * 32 + ch0);
        uint32_t u = *ap;
        float e0 = fmaxf(b2f((uint16_t)u) * sA + bA, 0.0f);
        float e1 = fmaxf(b2f((uint16_t)(u >> 16)) * sB + bB, 0.0f);
        *ap = (uint32_t)f2b(e0) | ((uint32_t)f2b(e1) << 16);
        m0 = fmaxf(m0, e0);
        m1 = fmaxf(m1, e1);
    }
    m0 = fmaxf(m0, __shfl_xor(m0, 16)); m0 = fmaxf(m0, __shfl_xor(m0, 32));
    m1 = fmaxf(m1, __shfl_xor(m1, 16)); m1 = fmaxf(m1, __shfl_xor(m1, 32));
    if (h == 0)
        xmaxV[(size_t)g * 16 + c2] = (uint32_t)f2b(m0) | ((uint32_t)f2b(m1) << 16);
}

// ---------------------------------------------------------------- W frags: bf16 hi/lo split of w1
__device__ __forceinline__ void load_wsplit(const float* __restrict__ w1, int cb,
                                            int l15, int lg, bf16x8* Bhi, bf16x8* Blo)
{
    int col = cb + l15;
    int kr  = lg * 8;
#pragma unroll
    for (int nb = 0; nb < 4; nb++) {
#pragma unroll
        for (int ks = 0; ks < 2; ks++) {
            U8 h, l;
#pragma unroll
            for (int jj = 0; jj < 8; jj++) {
                float w = w1[(ks * 32 + kr + jj) * 128 + col + nb * 16];
                uint16_t hb = f2b(w);
                h.u[jj] = hb;
                l.u[jj] = f2b(w - b2f(hb));
            }
            Bhi[nb * 2 + ks] = h.b;
            Blo[nb * 2 + ks] = l.b;
        }
    }
}

// ---------------------------------------------------------------- frag fetch (lower from XpL, upper from xmaxV via vS)
__device__ __forceinline__ void load_afrags(const uint16_t* __restrict__ XpL,
                                            const uint16_t* __restrict__ xmaxV,
                                            const int* __restrict__ vS,
                                            int tb, int rowSel, int l15, int lg,
                                            U8* aL, U8* aU)
{
#pragma unroll
    for (int m = 0; m < 2; m++) {
        int r = tb + rowSel * 32 + m * 16 + l15;
        int v = vS[r];                   // pad rows: -1 (memset)
        if (v >= 0) {
            aL[m].u = *(const u16x8*)(XpL + (size_t)r * 32 + lg * 8);
            aU[m].u = *(const u16x8*)(xmaxV + (size_t)v * 32 + lg * 8);
        } else {
#pragma unroll
            for (int j = 0; j < 8; j++) { aL[m].u[j] = 0; aU[m].u[j] = 0; }
        }
    }
}

// ---------------------------------------------------------------- kA: streaming stats GEMM (no barriers in loop)
__global__ __launch_bounds__(256)
void kA_stats(const uint16_t* __restrict__ XpL, const uint16_t* __restrict__ xmaxV,
              const float* __restrict__ w1, const int* __restrict__ vS,
              const int* __restrict__ np, float* __restrict__ sPart, int nwin2)
{
    __shared__ float fl[512];
    int t = threadIdx.x;
    int wv = t >> 6, lane = t & 63;
    int l15 = lane & 15, lg = lane >> 4;
    int rowSel = wv & 1, cb = (wv >> 1) * 64;

    bf16x8 Bhi[8], Blo[8];
    load_wsplit(w1, cb, l15, lg, Bhi, Blo);

    int nv = *np;
    float s[4] = {0.f, 0.f, 0.f, 0.f}, q[4] = {0.f, 0.f, 0.f, 0.f};

    for (int win = blockIdx.x; win < nwin2; win += gridDim.x) {
        int wb = win * 128;
        if (wb >= nv) break;
#pragma unroll
        for (int sub = 0; sub < 2; sub++) {
            int tb = wb + sub * 64;
            U8 aL[2], aU[2];
            load_afrags(XpL, xmaxV, vS, tb, rowSel, l15, lg, aL, aU);
            f32x4 acc[2][4];
#pragma unroll
            for (int m = 0; m < 2; m++)
#pragma unroll
                for (int nb = 0; nb < 4; nb++)
                    acc[m][nb] = (f32x4){0.f, 0.f, 0.f, 0.f};
#pragma unroll
            for (int m = 0; m < 2; m++)
#pragma unroll
                for (int nb = 0; nb < 4; nb++) {
                    acc[m][nb] = mfma16(aL[m].b, Bhi[nb * 2],     acc[m][nb]);
                    acc[m][nb] = mfma16(aL[m].b, Blo[nb * 2],     acc[m][nb]);
                    acc[m][nb] = mfma16(aU[m].b, Bhi[nb * 2 + 1], acc[m][nb]);
                    acc[m][nb] = mfma16(aU[m].b, Blo[nb * 2 + 1], acc[m][nb]);
                }
#pragma unroll
            for (int m = 0; m < 2; m++)
#pragma unroll
                for (int nb = 0; nb < 4; nb++)
#pragma unroll
                    for (int r = 0; r < 4; r++) {
                        float y = acc[m][nb][r];
                        s[nb] += y; q[nb] += y * y;
                    }
        }
    }
#pragma unroll
    for (int nb = 0; nb < 4; nb++) {
        s[nb] += __shfl_xor(s[nb], 16); s[nb] += __shfl_xor(s[nb], 32);
        q[nb] += __shfl_xor(q[nb], 16); q[nb] += __shfl_xor(q[nb], 32);
    }
    if (lane < 16) {
#pragma unroll
        for (int nb = 0; nb < 4; nb++) {
            int ch = cb + nb * 16 + lane;
            fl[rowSel * 128 + ch]       = s[nb];
            fl[256 + rowSel * 128 + ch] = q[nb];
        }
    }
    __syncthreads();
    if (t < 128)
        sPart[(size_t)t * NBA + blockIdx.x] = fl[t] + fl[128 + t];
    else {
        int ch = t - 128;
        sPart[(size_t)(128 + ch) * NBA + blockIdx.x] = fl[256 + ch] + fl[384 + ch];
    }
}

// ---------------------------------------------------------------- reduce stat partials
__global__ void k_red1(const float* __restrict__ part, float* __restrict__ stats1)
{
    __shared__ float red[4];
    int o = blockIdx.x, t = threadIdx.x;
    float s = 0.0f;
    for (int k = t; k < NBA; k += 256) s += part[(size_t)o * NBA + k];
#pragma unroll
    for (int m = 1; m < 64; m <<= 1) s += __shfl_xor(s, m);
    if ((t & 63) == 0) red[t >> 6] = s;
    __syncthreads();
    if (t == 0) stats1[o] = red[0] + red[1] + red[2] + red[3];
}

// ---------------------------------------------------------------- kB: MFMA GEMM + BN1 + ReLU + voxel gather-max
//      zero barriers; channel-major swizzled b128 stage/gather; scalar
//      flush-scan over register-resident voxel metadata
__global__ __launch_bounds__(256)
void kB_mapply(const uint16_t* __restrict__ XpL, const uint16_t* __restrict__ xmaxV,
               const float* __restrict__ w1, const int* __restrict__ vS,
               const int* __restrict__ vOff, const int* __restrict__ vCnt,
               const int* __restrict__ np, const float* __restrict__ sb1,
               float* __restrict__ outF, int ntiles)
{
    __shared__ float els[4][64 * CSTR];  // wave-private, channel-major (36.9KB)
    int t = threadIdx.x;
    int wv = t >> 6, lane = t & 63;
    int l15 = lane & 15, lg = lane >> 4;
    int rowSel = wv & 1, cb = (wv >> 1) * 64;
    float* ew = els[wv];

    bf16x8 Bhi[8], Blo[8];
    load_wsplit(w1, cb, l15, lg, Bhi, Blo);

    float sc[4], bc[4];
#pragma unroll
    for (int nb = 0; nb < 4; nb++) {
        int c = cb + nb * 16 + l15;
        sc[nb] = sb1[c];
        bc[nb] = sb1[128 + c];
    }

    int nv = *np;
    int grot = lane >> 3;                // gather slot rotation
    const float* ewl = ew + lane * CSTR; // gather: lane owns channel cb+lane

    for (int tile = blockIdx.x; tile < ntiles; tile += gridDim.x) {
        int tb = tile * 64;
        if (tb >= nv) break;             // uniform across block
        int tw = tb + rowSel * 32;       // this wave's 32-row window
        if (tw >= nv) continue;          // wave-uniform: window fully padded
        U8 aL[2], aU[2];
        load_afrags(XpL, xmaxV, vS, tb, rowSel, l15, lg, aL, aU);
        // gather metadata: voxels [gFirst,gLast] contiguous, nvox <= 32;
        // lane i preloads vOff/vCnt[gFirst+i] (latency hides under MFMAs)
        int lastRow = nv - 1 - tw; if (lastRow > 31) lastRow = 31;
        int rows   = lastRow + 1;
        int gFirst = vS[tw];
        int gLast  = vS[tw + lastRow];
        int nvox   = gLast - gFirst + 1;
        int myOff = 0, myCnt = 0;
        if (lane < nvox) {
            myOff = vOff[gFirst + lane];
            myCnt = vCnt[gFirst + lane];
        }
        int myEnd = myOff + myCnt;
        f32x4 acc[2][4];
#pragma unroll
        for (int m = 0; m < 2; m++)
#pragma unroll
            for (int nb = 0; nb < 4; nb++)
                acc[m][nb] = (f32x4){0.f, 0.f, 0.f, 0.f};
#pragma unroll
        for (int m = 0; m < 2; m++)
#pragma unroll
            for (int nb = 0; nb < 4; nb++) {
                acc[m][nb] = mfma16(aL[m].b, Bhi[nb * 2],     acc[m][nb]);
                acc[m][nb] = mfma16(aL[m].b, Blo[nb * 2],     acc[m][nb]);
                acc[m][nb] = mfma16(aU[m].b, Bhi[nb * 2 + 1], acc[m][nb]);
                acc[m][nb] = mfma16(aU[m].b, Blo[nb * 2 + 1], acc[m][nb]);
            }
        // stage BN1+ReLU to channel-major swizzled slice: 8 x ds_write_b128
        // addr = ci*36 + ((rowGroup + ci>>3)&7)*4 ; bank-even by design
#pragma unroll
        for (int m = 0; m < 2; m++) {
            int g = m * 4 + lg;          // row group 0..7
#pragma unroll
            for (int nb = 0; nb < 4; nb++) {
                int ci   = nb * 16 + l15;
                int slot = (g + (ci >> 3)) & 7;
                f32x4 vv;
#pragma unroll
                for (int r = 0; r < 4; r++)
                    vv[r] = fmaxf(acc[m][nb][r] * sc[nb] + bc[nb], 0.0f);
                *(f32x4*)(ew + ci * CSTR + slot * 4) = vv;
            }
        }
        // gather: linear scan of rows in b128 groups; flush at voxel ends
        int curIdx = 0;
        int curEnd = __builtin_amdgcn_readfirstlane(__shfl(myEnd, 0));
        float mx = 0.0f;
#pragma unroll
        for (int g4 = 0; g4 < 8; g4++) {
            int p0 = g4 * 4;
            if (p0 >= rows) break;       // wave-uniform
            f32x4 v = *(const f32x4*)(ewl + (((g4 + grot) & 7) << 2));
#pragma unroll
            for (int r = 0; r < 4; r++) {
                int p = p0 + r;
                if (tw + p == curEnd) {  // voxel boundary (wave-uniform)
                    int offv = __builtin_amdgcn_readfirstlane(__shfl(myOff, curIdx));
                    size_t oa = (size_t)(gFirst + curIdx) * 128 + cb + lane;
                    if (offv >= tw) outF[oa] = mx;   // endv<=tw+31 -> interior iff starts in-window
                    else if (mx > 0.0f)
                        atomicMax((unsigned int*)&outF[oa], __float_as_uint(mx));
                    curIdx++;
                    curEnd = (curIdx < nvox)
                           ? __builtin_amdgcn_readfirstlane(__shfl(myEnd, curIdx))
                           : 0x7fffffff;
                    mx = 0.0f;
                }
                if (p < rows) mx = fmaxf(mx, v[r]);
            }
        }
        if (curIdx < nvox) {             // final voxel
            int offv = __builtin_amdgcn_readfirstlane(__shfl(myOff, curIdx));
            int endv = __builtin_amdgcn_readfirstlane(__shfl(myEnd, curIdx));
            size_t oa = (size_t)(gFirst + curIdx) * 128 + cb + lane;
            if (offv >= tw && endv <= tw + 32) outF[oa] = mx;            // interior
            else if (mx > 0.0f)
                atomicMax((unsigned int*)&outF[oa], __float_as_uint(mx)); // straddler
        }
    }
}

// ---------------------------------------------------------------- launch
extern "C" void kernel_launch(void* const* d_in, const int* in_sizes, int n_in,
                              void* d_out, int out_size, void* d_ws, size_t ws_size,
                              hipStream_t stream)
{
    const float* pts = (const float*)d_in[0];
    const float* w0  = (const float*)d_in[1];
    const float* g0  = (const float*)d_in[2];
    const float* b0  = (const float*)d_in[3];
    const float* w1  = (const float*)d_in[4];
    const float* g1  = (const float*)d_in[5];
    const float* b1  = (const float*)d_in[6];

    int N      = in_sizes[0] / 5;
    int V      = out_size / 132;
    int Npad   = (N + 255) & ~255;
    int ntiles = Npad / 64;
    int nwin2  = (Npad + 127) / 128;

    char* ws = (char*)d_ws;
    size_t off = 0;
    auto alloc = [&](size_t bytes) { size_t r = off; off = (off + bytes + 255) & ~(size_t)255; return r; };

    float4* pts4    = (float4*)(ws + alloc((size_t)Npad * 16));
    int*    vS      = (int*)(ws + alloc((size_t)Npad * 4));
    size_t  zOff    = off;                                   // zero block start
    int*    cnt     = (int*)(ws + alloc((size_t)M_IDS * 4));
    int*    cursor  = (int*)(ws + alloc((size_t)M_IDS * 4));
    float*  stats   = (float*)(ws + alloc(320 * 4));         // bn0: 64 | bn1: 256
    int*    np      = (int*)(ws + alloc(4));
    size_t  zBytes  = off - zOff;
    int*    bOff    = (int*)(ws + alloc((size_t)M_IDS * 4));
    int*    idxArr  = (int*)(ws + alloc((size_t)M_IDS * 4));
    int*    vOff    = (int*)(ws + alloc((size_t)M_IDS * 4));
    int*    vCnt    = (int*)(ws + alloc((size_t)M_IDS * 4));
    int*    totO    = (int*)(ws + alloc(1024 * 4));
    int*    totC    = (int*)(ws + alloc(1024 * 4));
    int*    baseO   = (int*)(ws + alloc(1024 * 4));
    int*    baseC   = (int*)(ws + alloc(1024 * 4));
    float*  sb0     = (float*)(ws + alloc(64 * 4));
    float*  sb1     = (float*)(ws + alloc(256 * 4));
    float*  sPart   = (float*)(ws + alloc((size_t)256 * NBA * 4));
    float4* meanArr = (float4*)(ws + alloc((size_t)V * 16));
    uint16_t* XpL   = (uint16_t*)(ws + alloc((size_t)Npad * 32 * 2));
    uint16_t* xmaxV = (uint16_t*)(ws + alloc((size_t)V * 32 * 2));
    (void)ws_size;

    hipMemsetAsync(ws + zOff, 0, zBytes, stream);
    hipMemsetAsync(vS, 0xFF, (size_t)Npad * 4, stream);

    int blocksN = (N + 255) / 256;
    float* outF = (float*)d_out;

    k1_count<<<blocksN, 256, 0, stream>>>(pts, cnt, N);
    k2a_tot<<<NCHUNK, CH, 0, stream>>>(cnt, totO, totC, np);
    k2b_scan<<<1, 1024, 0, stream>>>(totO, totC, baseO, baseC);
    k2c_index<<<NCHUNK, CH, 0, stream>>>(cnt, baseO, baseC, idxArr, bOff, vOff, vCnt,
                                         outF, V);
    k3_order<<<blocksN, 256, 0, stream>>>(pts, bOff, idxArr, cursor, pts4, vS, N);
    k4_mean<<<(V + 255) / 256, 256, 0, stream>>>(pts4, vOff, vCnt, meanArr, V);
    k5_y0<<<1024, 256, 0, stream>>>(pts4, w0, vS, meanArr, XpL, stats, Npad);
    k_bnfin<<<1, 32, 0, stream>>>(stats, np, g0, b0, sb0, 32);
    k8_xmax<<<(V + 3) / 4, 256, 0, stream>>>(XpL, vOff, vCnt, sb0,
                                             (uint32_t*)xmaxV, V);
    kA_stats<<<NBA, 256, 0, stream>>>(XpL, xmaxV, w1, vS, np, sPart, nwin2);
    k_red1<<<256, 256, 0, stream>>>(sPart, stats + 64);
    k_bnfin<<<1, 128, 0, stream>>>(stats + 64, np, g1, b1, sb1, 128);
    kB_mapply<<<NBB, 256, 0, stream>>>(XpL, xmaxV, w1, vS, vOff, vCnt, np, sb1,
                                       outF, ntiles);
}